// Round 1
// baseline (1717.038 us; speedup 1.0000x reference)
//
#include <hip/hip_runtime.h>

using fp16 = _Float16;
typedef fp16 f16x2 __attribute__((ext_vector_type(2)));
typedef fp16 f16x4 __attribute__((ext_vector_type(4)));
typedef fp16 f16x8 __attribute__((ext_vector_type(8)));

#define DEVI __device__ __forceinline__

constexpr int LL = 50;      // L and T
constexpr int BB = 4096;    // batch
constexpr int ALPHA = 128;
constexpr int TAGD = 64;
constexpr int EMB = 40;
constexpr int CTX = 20;
constexpr int ATT = 100;
constexpr int FREQ = 60;

constexpr int QC  = 152;    // q-input padded  (128 probs | 20 ctx | 4 pad)
constexpr int FFC = 208;    // ff-input        (128 probs | 60 in_attn | 20 ctx)
constexpr int KP  = 104;    // ATT padded to mult of 8
constexpr int VP  = 52;     // L padded to mult of 4
constexpr int K_ELE = LL*KP;   // 5200
constexpr int V_ELE = 60*VP;   // 3120

// packed-weight element offsets (fp16 elements)
constexpr int PW_Q  = 0;                    // WqT  [100][152]
constexpr int PW_FF = PW_Q  + ATT*QC;       // WffT [128][208]
constexpr int PW_RE = PW_FF + ALPHA*FFC;    // WreT [20][128]
constexpr int PW_BC = PW_RE + CTX*128;      // WbcT [20][24]
constexpr int PW_TOT= PW_BC + CTX*24;       // 44864
constexpr size_t WSZ_W = (size_t)PW_TOT*2;  // 89728 B

// workspace byte offsets
constexpr size_t WS_W  = 0;
constexpr size_t WS_K  = WS_W  + WSZ_W;                  // f16 [4096][5200]
constexpr size_t WS_V  = WS_K  + (size_t)BB*K_ELE*2;     // f16 [4096][3120]
constexpr size_t WS_CT = WS_V  + (size_t)BB*V_ELE*2;     // f32 [50][4096][20] ctxt
constexpr size_t WS_TQ = WS_CT + (size_t)LL*BB*CTX*4;    // f16 [4096][100]
constexpr size_t WS_TF = WS_TQ + (size_t)BB*ATT*2;       // f16 [4096][128]
constexpr size_t WS_PQ = WS_TF + (size_t)BB*ALPHA*2;     // f32 [50][100]
constexpr size_t WS_PK = WS_PQ + (size_t)LL*ATT*4;       // f32 [50][100]
constexpr size_t WS_CE = WS_PK + (size_t)LL*ATT*4;       // f32 [128][20]

// decoder LDS byte offsets
constexpr int SM_K   = 89728;
constexpr int SM_V   = 131328;
constexpr int SM_QIN = 156288;
constexpr int SM_FFI = 157504;
constexpr int SM_QH  = 159168;
constexpr int SM_AT  = 160000;
constexpr int SM_RPP = 160416;
constexpr int SM_TQ  = 160608;
constexpr int SM_TF  = 161408;
constexpr int SM_RED = 162432;
constexpr int SM_TOT = 162496;   // <= 163840

DEVI float sigm(float x) { return 1.0f / (1.0f + __expf(-x)); }

DEVI float dot8f(f16x8 a, f16x8 b, float acc) {
#if __has_builtin(__builtin_amdgcn_fdot2)
  acc = __builtin_amdgcn_fdot2(__builtin_shufflevector(a,a,0,1), __builtin_shufflevector(b,b,0,1), acc, false);
  acc = __builtin_amdgcn_fdot2(__builtin_shufflevector(a,a,2,3), __builtin_shufflevector(b,b,2,3), acc, false);
  acc = __builtin_amdgcn_fdot2(__builtin_shufflevector(a,a,4,5), __builtin_shufflevector(b,b,4,5), acc, false);
  acc = __builtin_amdgcn_fdot2(__builtin_shufflevector(a,a,6,7), __builtin_shufflevector(b,b,6,7), acc, false);
#else
  #pragma unroll
  for (int k = 0; k < 8; ++k) acc += (float)a[k]*(float)b[k];
#endif
  return acc;
}

DEVI float dot4f(f16x4 a, f16x4 b, float acc) {
#if __has_builtin(__builtin_amdgcn_fdot2)
  acc = __builtin_amdgcn_fdot2(__builtin_shufflevector(a,a,0,1), __builtin_shufflevector(b,b,0,1), acc, false);
  acc = __builtin_amdgcn_fdot2(__builtin_shufflevector(a,a,2,3), __builtin_shufflevector(b,b,2,3), acc, false);
#else
  #pragma unroll
  for (int k = 0; k < 4; ++k) acc += (float)a[k]*(float)b[k];
#endif
  return acc;
}

DEVI float wredmax(float v) {
  #pragma unroll
  for (int o = 32; o > 0; o >>= 1) v = fmaxf(v, __shfl_xor(v, o, 64));
  return v;
}
DEVI float wredsum(float v) {
  #pragma unroll
  for (int o = 32; o > 0; o >>= 1) v += __shfl_xor(v, o, 64);
  return v;
}

// ---------------- setup: pos tables, ce_table, packed weights ----------------
__global__ void dt_setup(const float* __restrict__ embT, const float* __restrict__ Wce,
                         const float* __restrict__ bce,
                         const float* __restrict__ Wq, const float* __restrict__ bq,
                         const float* __restrict__ Wk, const float* __restrict__ bk,
                         const float* __restrict__ Wff, const float* __restrict__ Wre,
                         const float* __restrict__ Wbc, char* __restrict__ ws) {
  __shared__ float ap[LL*FREQ];
  const int tid = threadIdx.x, bid = blockIdx.x;
  if (bid <= 1) {
    for (int i = tid; i < LL*(FREQ/2); i += 256) {
      int p = i / 30, k = i % 30;
      float freq = powf(10000.f, 2.0f*(float)k/60.0f);
      float ang = (float)p / freq;
      ap[p*FREQ + k]      = sinf(ang);
      ap[p*FREQ + 30 + k] = cosf(ang);
    }
    __syncthreads();
    if (bid == 0) {
      float* pq = (float*)(ws + WS_PQ);
      for (int i = tid; i < LL*ATT; i += 256) {
        int r = i / ATT, j = i % ATT;
        float a = bq[j];
        for (int f = 0; f < FREQ; ++f) a += ap[r*FREQ + f]*Wq[f*ATT + j];
        pq[i] = a;
      }
    } else {
      float* pk = (float*)(ws + WS_PK);
      for (int i = tid; i < LL*ATT; i += 256) {
        int r = i / ATT, j = i % ATT;
        float a = bk[j];
        for (int f = 0; f < FREQ; ++f) a += ap[r*FREQ + f]*Wk[f*ATT + j];
        pk[i] = a;
      }
    }
  } else if (bid == 2) {
    float* ce = (float*)(ws + WS_CE);
    for (int i = tid; i < ALPHA*CTX; i += 256) {
      int r = i / CTX, o = i % CTX;
      float a = bce[o];
      for (int e = 0; e < EMB; ++e) a += embT[r*EMB + e]*Wce[e*CTX + o];
      ce[i] = a;
    }
  } else {
    fp16* pw = (fp16*)(ws + WS_W);
    for (int gi = (bid-3)*256 + tid; gi < PW_TOT; gi += 61*256) {
      float v = 0.f;
      if (gi < PW_FF) {                       // WqT[j][c]
        int j = gi / QC, c = gi % QC;
        if (c < 128)      v = Wq[(80 + c)*ATT + j];          // probs rows
        else if (c < 148) v = Wq[(60 + (c-128))*ATT + j];    // ctx rows
      } else if (gi < PW_RE) {                // WffT[o][c]
        int t = gi - PW_FF; int o = t / FFC, c = t % FFC;
        if (c < 128)      v = Wff[(228 + c)*ALPHA + o];      // probs rows
        else if (c < 188) v = Wff[(c - 128)*ALPHA + o];      // in_attn rows
        else              v = Wff[(208 + (c-188))*ALPHA + o];// ctx rows
      } else if (gi < PW_BC) {                // WreT[o][c]
        int t = gi - PW_RE;
        v = Wre[(t % 128)*CTX + (t / 128)];
      } else {                                // WbcT[o][c]
        int t = gi - PW_BC; int o = t / 24, c = t % 24;
        if (c < 20) v = Wbc[c*CTX + o];
      }
      pw[gi] = (fp16)v;
    }
  }
}

// ---------------- tags precompute: tag_q, tag_ff(+b_ff) ----------------
__global__ void dt_tags(const float* __restrict__ tags, const float* __restrict__ Wq,
                        const float* __restrict__ Wff, const float* __restrict__ bff,
                        char* __restrict__ ws) {
  __shared__ float tg[TAGD];
  const int b = blockIdx.x, tid = threadIdx.x;
  if (tid < TAGD) tg[tid] = tags[b*TAGD + tid];
  __syncthreads();
  if (tid < ATT) {
    float a = 0.f;
    for (int c = 0; c < TAGD; ++c) a += tg[c]*Wq[(208 + c)*ATT + tid];
    ((fp16*)(ws + WS_TQ))[(size_t)b*ATT + tid] = (fp16)a;
  } else if (tid < ATT + ALPHA) {
    int o = tid - ATT;
    float a = bff[o];
    for (int c = 0; c < TAGD; ++c) a += tg[c]*Wff[(356 + c)*ALPHA + o];
    ((fp16*)(ws + WS_TF))[(size_t)b*ALPHA + o] = (fp16)a;
  }
}

// ---------------- encoder: ctxt ----------------
__global__ void dt_enc_ctxt(const int* __restrict__ lemma,
    const float* __restrict__ Wb4, const float* __restrict__ bb4,
    const float* __restrict__ Waft, const float* __restrict__ baft,
    const float* __restrict__ Wall, const float* __restrict__ ball,
    char* __restrict__ ws) {
  __shared__ float cet[ALPHA*CTX];
  __shared__ float wb4[40*20], wa[20*20], wl[40*20];
  __shared__ float bi4[20], biA[20], biL[20];
  const float* ceT = (const float*)(ws + WS_CE);
  const int tid = threadIdx.x;
  for (int i = tid; i < ALPHA*CTX; i += 256) cet[i] = ceT[i];
  for (int i = tid; i < 800; i += 256) wb4[i] = Wb4[i];
  for (int i = tid; i < 400; i += 256) wa[i] = Waft[i];
  for (int i = tid; i < 800; i += 256) wl[i] = Wall[i];
  if (tid < 20) { bi4[tid] = bb4[tid]; biA[tid] = baft[tid]; biL[tid] = ball[tid]; }
  __syncthreads();
  const int g = blockIdx.x*256 + tid;     // exactly 50*4096
  const int l = g / BB, b = g % BB;
  const int im2 = (l >= 2)    ? lemma[(l-2)*BB + b] : -1;
  const int im1 = (l >= 1)    ? lemma[(l-1)*BB + b] : -1;
  const int ip1 = (l < LL-1)  ? lemma[(l+1)*BB + b] : -1;
  float c2[CTX], c1[CTX], cf[CTX];
  #pragma unroll
  for (int c = 0; c < CTX; ++c) {
    c2[c] = (im2 >= 0) ? cet[im2*CTX + c] : 0.f;
    c1[c] = (im1 >= 0) ? cet[im1*CTX + c] : 0.f;
    cf[c] = (ip1 >= 0) ? cet[ip1*CTX + c] : 0.f;
  }
  float bv[CTX], av[CTX];
  #pragma unroll
  for (int o = 0; o < CTX; ++o) {
    float a = bi4[o];
    #pragma unroll
    for (int c = 0; c < CTX; ++c) a += c2[c]*wb4[c*CTX + o] + c1[c]*wb4[(CTX+c)*CTX + o];
    bv[o] = sigm(a);
  }
  #pragma unroll
  for (int o = 0; o < CTX; ++o) {
    float a = biA[o];
    #pragma unroll
    for (int c = 0; c < CTX; ++c) a += cf[c]*wa[c*CTX + o];
    av[o] = sigm(a);
  }
  float* ct = (float*)(ws + WS_CT);
  #pragma unroll
  for (int o = 0; o < CTX; ++o) {
    float a = biL[o];
    #pragma unroll
    for (int c = 0; c < CTX; ++c) a += bv[c]*wl[c*CTX + o] + av[c]*wl[(CTX+c)*CTX + o];
    ct[(size_t)g*CTX + o] = sigm(a);
  }
}

// ---------------- encoder: K (sigmoid keys) and V (packed, padded, f16) ----------------
__global__ void dt_enc_kv(const int* __restrict__ lemma, const float* __restrict__ embT,
                          const float* __restrict__ Wk, char* __restrict__ ws) {
  __shared__ float ctl[LL*CTX];
  __shared__ float eml[LL*EMB];
  __shared__ float wk[60*ATT];
  __shared__ int lem[LL];
  const int b = blockIdx.x, tid = threadIdx.x;
  const float* ct = (const float*)(ws + WS_CT);
  const float* pk = (const float*)(ws + WS_PK);
  if (tid < LL) lem[tid] = lemma[tid*BB + b];
  for (int i = tid; i < LL*CTX; i += 256) {
    int l = i / CTX; ctl[i] = ct[(size_t)(l*BB + b)*CTX + (i % CTX)];
  }
  for (int i = tid; i < 60*ATT; i += 256) wk[i] = Wk[(60 + i/ATT)*ATT + (i % ATT)];
  __syncthreads();
  for (int i = tid; i < LL*EMB; i += 256) {
    int l = i / EMB; eml[i] = embT[lem[l]*EMB + (i % EMB)];
  }
  __syncthreads();
  fp16* Kw = (fp16*)(ws + WS_K) + (size_t)b*K_ELE;
  for (int i = tid; i < K_ELE; i += 256) {
    int l = i / KP, a = i % KP;
    fp16 v = (fp16)0.f;
    if (a < ATT) {
      float acc = pk[l*ATT + a];
      #pragma unroll
      for (int c = 0; c < CTX; ++c) acc += ctl[l*CTX + c]*wk[c*ATT + a];
      #pragma unroll
      for (int e = 0; e < EMB; ++e) acc += eml[l*EMB + e]*wk[(CTX + e)*ATT + a];
      v = (fp16)sigm(acc);
    }
    Kw[i] = v;
  }
  fp16* Vw = (fp16*)(ws + WS_V) + (size_t)b*V_ELE;
  for (int i = tid; i < V_ELE; i += 256) {
    int d = i / VP, l = i % VP;
    float v = 0.f;
    if (l < LL) v = (d < CTX) ? ctl[l*CTX + d] : eml[l*EMB + (d - CTX)];
    Vw[i] = (fp16)v;
  }
}

// ---------------- decoder: persistent 49-step recurrence, 4 batch elems / block ----------------
__global__ __launch_bounds__(256, 1)
void dt_decoder(const char* __restrict__ ws, const float* __restrict__ b_re,
                const float* __restrict__ b_bc, float* __restrict__ out) {
  extern __shared__ char sm[];
  fp16* wlds = (fp16*)sm;                    // packed weights image
  fp16* Kl   = (fp16*)(sm + SM_K);           // [4][50][104]
  fp16* Vl   = (fp16*)(sm + SM_V);           // [4][60][52]
  fp16* qin  = (fp16*)(sm + SM_QIN);         // [4][152]  (probs|ctx|pad)
  fp16* ffin = (fp16*)(sm + SM_FFI);         // [4][208]  (probs|in_attn|ctx)
  fp16* qh   = (fp16*)(sm + SM_QH);          // [4][104]
  fp16* ath  = (fp16*)(sm + SM_AT);          // [4][52]
  fp16* rpp  = (fp16*)(sm + SM_RPP);         // [4][24]
  fp16* tq   = (fp16*)(sm + SM_TQ);          // [4][100]
  fp16* tf   = (fp16*)(sm + SM_TF);          // [4][128]
  float* redm = (float*)(sm + SM_RED);       // [8]
  float* reds = redm + 8;                    // [8]

  const int tid = threadIdx.x, lane = tid & 63, w = tid >> 6;
  const int b0 = blockIdx.x * 4;
  const float* posq = (const float*)(ws + WS_PQ);

  // ---- stage LDS ----
  { const uint4* s = (const uint4*)(ws + WS_W); uint4* d = (uint4*)sm;
    for (int i = tid; i < (int)(WSZ_W/16); i += 256) d[i] = s[i]; }
  { const uint4* s = (const uint4*)(ws + WS_K + (size_t)b0*K_ELE*2); uint4* d = (uint4*)Kl;
    for (int i = tid; i < 4*K_ELE*2/16; i += 256) d[i] = s[i]; }
  { const uint4* s = (const uint4*)(ws + WS_V + (size_t)b0*V_ELE*2); uint4* d = (uint4*)Vl;
    for (int i = tid; i < 4*V_ELE*2/16; i += 256) d[i] = s[i]; }
  { const unsigned* s = (const unsigned*)(ws + WS_TQ + (size_t)b0*ATT*2); unsigned* d = (unsigned*)tq;
    for (int i = tid; i < 4*ATT*2/4; i += 256) d[i] = s[i]; }
  { const unsigned* s = (const unsigned*)(ws + WS_TF + (size_t)b0*ALPHA*2); unsigned* d = (unsigned*)tf;
    for (int i = tid; i < 4*ALPHA*2/4; i += 256) d[i] = s[i]; }
  // zero state (incl. pads), then one-hot start token
  { unsigned* z = (unsigned*)qin;  for (int i = tid; i < 4*QC/2;  i += 256) z[i] = 0; }
  { unsigned* z = (unsigned*)ffin; for (int i = tid; i < 4*FFC/2; i += 256) z[i] = 0; }
  { unsigned* z = (unsigned*)qh;   for (int i = tid; i < 4*KP/2;  i += 256) z[i] = 0; }
  { unsigned* z = (unsigned*)ath;  for (int i = tid; i < 4*VP/2;  i += 256) z[i] = 0; }
  { unsigned* z = (unsigned*)rpp;  for (int i = tid; i < 4*24/2;  i += 256) z[i] = 0; }
  if (tid < 4) { qin[tid*QC + 1] = (fp16)1.f; ffin[tid*FFC + 1] = (fp16)1.f; }
  // output row 0 = one-hot start
  for (int i = tid; i < 512; i += 256) {
    int bw = i >> 7, o = i & 127;
    out[(size_t)(b0 + bw)*ALPHA + o] = (o == 1) ? 1.f : 0.f;
  }
  float bre_r = 0.f, bbc_r = 0.f;
  if (lane < CTX) { bre_r = b_re[lane]; bbc_r = b_bc[lane]; }
  __syncthreads();

  for (int i = 1; i < LL; ++i) {
    // ---- P1 (wave-local, b = w): ctx from r_pp; r_new from OLD probs ----
    if (lane < CTX) {
      const fp16* rp = rpp + w*24;
      const fp16* wb = wlds + PW_BC + lane*24;
      float a1 = bbc_r;
      #pragma unroll
      for (int k = 0; k < 3; ++k)
        a1 = dot8f(*(const f16x8*)(rp + 8*k), *(const f16x8*)(wb + 8*k), a1);
      float ctxv = sigm(a1);
      const fp16* pp = qin + w*QC;           // probs at offset 0
      const fp16* wr = wlds + PW_RE + lane*128;
      float a2 = bre_r;
      #pragma unroll
      for (int k = 0; k < 16; ++k)
        a2 = dot8f(*(const f16x8*)(pp + 8*k), *(const f16x8*)(wr + 8*k), a2);
      float rnew = sigm(a2);
      qin[w*QC + 128 + lane]  = (fp16)ctxv;
      ffin[w*FFC + 188 + lane] = (fp16)ctxv;
      rpp[w*24 + lane] = (fp16)rnew;
    }
    __syncthreads();

    // ---- P2: q = sigm(qin @ WqT) ; each thread: one j, two b ----
    {
      const int jj = lane + ((w & 1) << 6);
      const int bl = (w >> 1) << 1;
      if (jj < ATT) {
        float pj = posq[i*ATT + jj];
        float aA = pj + (float)tq[bl*ATT + jj];
        float aB = pj + (float)tq[(bl+1)*ATT + jj];
        const fp16* wq = wlds + PW_Q + jj*QC;
        const fp16* xA = qin + bl*QC;
        const fp16* xB = qin + (bl+1)*QC;
        for (int k = 0; k < QC/8; ++k) {
          f16x8 wv = *(const f16x8*)(wq + 8*k);
          aA = dot8f(*(const f16x8*)(xA + 8*k), wv, aA);
          aB = dot8f(*(const f16x8*)(xB + 8*k), wv, aB);
        }
        qh[bl*KP + jj]     = (fp16)sigm(aA);
        qh[(bl+1)*KP + jj] = (fp16)sigm(aB);
      }
    }
    __syncthreads();

    // ---- P3 (b = w): scores + softmax over 50 positions ----
    {
      float s = -1e30f;
      if (lane < LL) {
        const fp16* qv = qh + w*KP;
        const fp16* kr = Kl + w*K_ELE + lane*KP;
        float a = 0.f;
        #pragma unroll
        for (int k = 0; k < KP/8; ++k)
          a = dot8f(*(const f16x8*)(qv + 8*k), *(const f16x8*)(kr + 8*k), a);
        s = a;
      }
      float m  = wredmax(s);
      float e  = (lane < LL) ? __expf(s - m) : 0.f;
      float su = wredsum(e);
      if (lane < LL) ath[w*VP + lane] = (fp16)(e / su);
    }
    __syncthreads();

    // ---- P4 (b = w): in_attn = attn @ V ----
    if (lane < 60) {
      const fp16* ar = ath + w*VP;
      const fp16* vr = Vl + w*V_ELE + lane*VP;
      float a = 0.f;
      #pragma unroll
      for (int k = 0; k < VP/4; ++k)
        a = dot4f(*(const f16x4*)(ar + 4*k), *(const f16x4*)(vr + 4*k), a);
      ffin[w*FFC + 128 + lane] = (fp16)a;
    }
    __syncthreads();

    // ---- P5: p = softmax(sigm(ffin @ WffT)); write out + new probs ----
    {
      const int o  = lane + ((w & 1) << 6);
      const int bl = (w >> 1) << 1;
      float aA = (float)tf[bl*ALPHA + o];
      float aB = (float)tf[(bl+1)*ALPHA + o];
      const fp16* wf = wlds + PW_FF + o*FFC;
      const fp16* xA = ffin + bl*FFC;
      const fp16* xB = ffin + (bl+1)*FFC;
      for (int k = 0; k < FFC/8; ++k) {
        f16x8 wv = *(const f16x8*)(wf + 8*k);
        aA = dot8f(*(const f16x8*)(xA + 8*k), wv, aA);
        aB = dot8f(*(const f16x8*)(xB + 8*k), wv, aB);
      }
      float sA = sigm(aA), sB = sigm(aB);
      float mA = wredmax(sA), mB = wredmax(sB);
      if (lane == 0) { redm[bl*2 + (w&1)] = mA; redm[(bl+1)*2 + (w&1)] = mB; }
      __syncthreads();
      float MA = fmaxf(redm[bl*2], redm[bl*2 + 1]);
      float MB = fmaxf(redm[(bl+1)*2], redm[(bl+1)*2 + 1]);
      float eA = __expf(sA - MA), eB = __expf(sB - MB);
      float uA = wredsum(eA), uB = wredsum(eB);
      if (lane == 0) { reds[bl*2 + (w&1)] = uA; reds[(bl+1)*2 + (w&1)] = uB; }
      __syncthreads();
      float pA = eA / (reds[bl*2] + reds[bl*2 + 1]);
      float pB = eB / (reds[(bl+1)*2] + reds[(bl+1)*2 + 1]);
      out[((size_t)i*BB + (b0 + bl))*ALPHA + o]     = pA;
      out[((size_t)i*BB + (b0 + bl + 1))*ALPHA + o] = pB;
      qin[bl*QC + o]      = (fp16)pA;  qin[(bl+1)*QC + o]  = (fp16)pB;
      ffin[bl*FFC + o]    = (fp16)pA;  ffin[(bl+1)*FFC + o] = (fp16)pB;
    }
    __syncthreads();
  }
}

extern "C" void kernel_launch(void* const* d_in, const int* in_sizes, int n_in,
                              void* d_out, int out_size, void* d_ws, size_t ws_size,
                              hipStream_t stream) {
  const int*   lemma = (const int*)  d_in[0];
  const float* tags  = (const float*)d_in[1];
  const float* embT  = (const float*)d_in[2];
  const float* Wce   = (const float*)d_in[3];
  const float* bce   = (const float*)d_in[4];
  const float* Wb4   = (const float*)d_in[5];
  const float* bb4   = (const float*)d_in[6];
  const float* Waft  = (const float*)d_in[7];
  const float* baft  = (const float*)d_in[8];
  const float* Wall  = (const float*)d_in[9];
  const float* ball  = (const float*)d_in[10];
  const float* Wre   = (const float*)d_in[11];
  const float* bre   = (const float*)d_in[12];
  const float* Wbc   = (const float*)d_in[13];
  const float* bbc   = (const float*)d_in[14];
  const float* Wq    = (const float*)d_in[15];
  const float* bq    = (const float*)d_in[16];
  const float* Wk    = (const float*)d_in[17];
  const float* bk    = (const float*)d_in[18];
  const float* Wff   = (const float*)d_in[19];
  const float* bff   = (const float*)d_in[20];
  char* ws = (char*)d_ws;
  float* out = (float*)d_out;

  hipFuncSetAttribute((const void*)dt_decoder,
                      hipFuncAttributeMaxDynamicSharedMemorySize, SM_TOT);

  dt_setup<<<64, 256, 0, stream>>>(embT, Wce, bce, Wq, bq, Wk, bk, Wff, Wre, Wbc, ws);
  dt_tags<<<BB, 256, 0, stream>>>(tags, Wq, Wff, bff, ws);
  dt_enc_ctxt<<<LL*BB/256, 256, 0, stream>>>(lemma, Wb4, bb4, Waft, baft, Wall, ball, ws);
  dt_enc_kv<<<BB, 256, 0, stream>>>(lemma, embT, Wk, ws);
  dt_decoder<<<BB/4, 256, SM_TOT, stream>>>(ws, bre, bbc, out);
}

// Round 2
// 1051.172 us; speedup vs baseline: 1.6335x; 1.6335x over previous
//
#include <hip/hip_runtime.h>

using fp16 = _Float16;
typedef fp16 f16x2 __attribute__((ext_vector_type(2)));
typedef fp16 f16x4 __attribute__((ext_vector_type(4)));
typedef fp16 f16x8 __attribute__((ext_vector_type(8)));

#define DEVI __device__ __forceinline__

constexpr int LL = 50;      // L and T
constexpr int BB = 4096;    // batch
constexpr int ALPHA = 128;
constexpr int EMB = 40;
constexpr int CTX = 20;
constexpr int ATT = 100;
constexpr int FREQ = 60;

constexpr int QC  = 152;    // q-input row   (128 probs | 20 ctx | 4 pad)   304B = 16*19 ✓
constexpr int FFC = 216;    // ff-input row  (128 probs | 60 attn | 20 ctx | 8 pad) 432B = 16*27 ✓
constexpr int REC = 136;    // Wre row (128 + 8 pad)                        272B = 16*17 ✓
constexpr int BCC = 40;     // Wbc row (20 + 20 pad)                        80B  = 16*5  ✓
constexpr int KTC = 72;     // WkT / tag-weight rows (60|64 + pad)          144B = 16*9  ✓
constexpr int KP  = 104;    // K row: ATT padded (208B = 16*13 ✓)
constexpr int VP  = 52;     // V row: L padded to mult of 4
constexpr int K_ELE = LL*KP;   // 5200
constexpr int V_ELE = 60*VP;   // 3120

// packed-weight element offsets (fp16 elements)
constexpr int PW_Q   = 0;                     // WqT   [100][152]
constexpr int PW_FF  = PW_Q   + ATT*QC;       // WffT  [128][216]
constexpr int PW_RE  = PW_FF  + ALPHA*FFC;    // WreT  [20][136]
constexpr int PW_BC  = PW_RE  + CTX*REC;      // WbcT  [20][40]
constexpr int PW_KT  = PW_BC  + CTX*BCC;      // WkT   [100][72]   (enc only)
constexpr int PW_TGQ = PW_KT  + ATT*KTC;      // WqTgT [100][72]   (tags only)
constexpr int PW_TGF = PW_TGQ + ATT*KTC;      // WffTgT[128][72]   (tags only)
constexpr int PW_TOT = PW_TGF + ALPHA*KTC;    // 69984
constexpr int PW_DEC = PW_BC  + CTX*BCC;      // 46368 staged into decoder LDS
constexpr size_t WSZ_W = (size_t)PW_TOT*2;    // 139968 B

// workspace byte offsets
constexpr size_t WS_W  = 0;
constexpr size_t WS_K  = WS_W  + WSZ_W;                  // f16 [4096][5200]
constexpr size_t WS_V  = WS_K  + (size_t)BB*K_ELE*2;     // f16 [4096][3120]
constexpr size_t WS_CT = WS_V  + (size_t)BB*V_ELE*2;     // f32 [50][4096][20] ctxt
constexpr size_t WS_TQ = WS_CT + (size_t)LL*BB*CTX*4;    // f16 [4096][100]
constexpr size_t WS_TF = WS_TQ + (size_t)BB*ATT*2;       // f16 [4096][128]
constexpr size_t WS_PQ = WS_TF + (size_t)BB*ALPHA*2;     // f32 [50][100]
constexpr size_t WS_PK = WS_PQ + (size_t)LL*ATT*4;       // f32 [50][100]
constexpr size_t WS_CE = WS_PK + (size_t)LL*ATT*4;       // f32 [128][20]

// decoder LDS layout
constexpr int SM_W   = 0;                   // 92736 B packed weights (PW_DEC)
constexpr int SM_PQ  = PW_DEC*2;            // 92736: posq f32 [50][100] = 20000 B
constexpr int SM_WV  = SM_PQ + 20000;       // 112736: per-wave state, 1600 B x 8
constexpr int WV_STRIDE = 800;              // f16 elems per wave region
// per-wave offsets (f16 elems); all 16B-aligned
constexpr int XQ_O = 0;      // [152] probs|ctx|pad
constexpr int XF_O = 152;    // [216] probs|attn|ctx|pad
constexpr int Q_O  = 368;    // [104]
constexpr int AT_O = 472;    // [56]
constexpr int RPP_O= 528;    // [24]
constexpr int TQ_O = 552;    // [104]
constexpr int TF_O = 656;    // [128] -> end 784
constexpr int SM_TOT = SM_WV + 8*WV_STRIDE*2;   // 125536 <= 163840

DEVI float sigm(float x) { return 1.0f / (1.0f + __expf(-x)); }

DEVI float dot8f(f16x8 a, f16x8 b, float acc) {
#if __has_builtin(__builtin_amdgcn_fdot2)
  acc = __builtin_amdgcn_fdot2(__builtin_shufflevector(a,a,0,1), __builtin_shufflevector(b,b,0,1), acc, false);
  acc = __builtin_amdgcn_fdot2(__builtin_shufflevector(a,a,2,3), __builtin_shufflevector(b,b,2,3), acc, false);
  acc = __builtin_amdgcn_fdot2(__builtin_shufflevector(a,a,4,5), __builtin_shufflevector(b,b,4,5), acc, false);
  acc = __builtin_amdgcn_fdot2(__builtin_shufflevector(a,a,6,7), __builtin_shufflevector(b,b,6,7), acc, false);
#else
  #pragma unroll
  for (int k = 0; k < 8; ++k) acc += (float)a[k]*(float)b[k];
#endif
  return acc;
}

DEVI float dot4f(f16x4 a, f16x4 b, float acc) {
#if __has_builtin(__builtin_amdgcn_fdot2)
  acc = __builtin_amdgcn_fdot2(__builtin_shufflevector(a,a,0,1), __builtin_shufflevector(b,b,0,1), acc, false);
  acc = __builtin_amdgcn_fdot2(__builtin_shufflevector(a,a,2,3), __builtin_shufflevector(b,b,2,3), acc, false);
#else
  #pragma unroll
  for (int k = 0; k < 4; ++k) acc += (float)a[k]*(float)b[k];
#endif
  return acc;
}

DEVI float wredmax(float v) {
  #pragma unroll
  for (int o = 32; o > 0; o >>= 1) v = fmaxf(v, __shfl_xor(v, o, 64));
  return v;
}
DEVI float wredsum(float v) {
  #pragma unroll
  for (int o = 32; o > 0; o >>= 1) v += __shfl_xor(v, o, 64);
  return v;
}

// ---------------- setup: pos tables, ce_table, packed weights ----------------
__global__ void dt_setup(const float* __restrict__ embT, const float* __restrict__ Wce,
                         const float* __restrict__ bce,
                         const float* __restrict__ Wq, const float* __restrict__ bq,
                         const float* __restrict__ Wk, const float* __restrict__ bk,
                         const float* __restrict__ Wff, const float* __restrict__ Wre,
                         const float* __restrict__ Wbc, char* __restrict__ ws) {
  __shared__ float ap[LL*FREQ];
  const int tid = threadIdx.x, bid = blockIdx.x;
  if (bid <= 1) {
    for (int i = tid; i < LL*(FREQ/2); i += 256) {
      int p = i / 30, k = i % 30;
      float freq = powf(10000.f, 2.0f*(float)k/60.0f);
      float ang = (float)p / freq;
      ap[p*FREQ + k]      = sinf(ang);
      ap[p*FREQ + 30 + k] = cosf(ang);
    }
    __syncthreads();
    if (bid == 0) {
      float* pq = (float*)(ws + WS_PQ);
      for (int i = tid; i < LL*ATT; i += 256) {
        int r = i / ATT, j = i % ATT;
        float a = bq[j];
        for (int f = 0; f < FREQ; ++f) a += ap[r*FREQ + f]*Wq[f*ATT + j];
        pq[i] = a;
      }
    } else {
      float* pk = (float*)(ws + WS_PK);
      for (int i = tid; i < LL*ATT; i += 256) {
        int r = i / ATT, j = i % ATT;
        float a = bk[j];
        for (int f = 0; f < FREQ; ++f) a += ap[r*FREQ + f]*Wk[f*ATT + j];
        pk[i] = a;
      }
    }
  } else if (bid == 2) {
    float* ce = (float*)(ws + WS_CE);
    for (int i = tid; i < ALPHA*CTX; i += 256) {
      int r = i / CTX, o = i % CTX;
      float a = bce[o];
      for (int e = 0; e < EMB; ++e) a += embT[r*EMB + e]*Wce[e*CTX + o];
      ce[i] = a;
    }
  } else {
    fp16* pw = (fp16*)(ws + WS_W);
    for (int gi = (bid-3)*256 + tid; gi < PW_TOT; gi += 61*256) {
      float v = 0.f;
      if (gi < PW_FF) {                       // WqT[j][c], stride 152
        int j = gi / QC, c = gi % QC;
        if (c < 128)      v = Wq[(80 + c)*ATT + j];
        else if (c < 148) v = Wq[(60 + (c-128))*ATT + j];
      } else if (gi < PW_RE) {                // WffT[o][c], stride 216
        int t = gi - PW_FF; int o = t / FFC, c = t % FFC;
        if (c < 128)      v = Wff[(228 + c)*ALPHA + o];
        else if (c < 188) v = Wff[(c - 128)*ALPHA + o];
        else if (c < 208) v = Wff[(208 + (c-188))*ALPHA + o];
      } else if (gi < PW_BC) {                // WreT[o][c], stride 136
        int t = gi - PW_RE; int o = t / REC, c = t % REC;
        if (c < 128) v = Wre[c*CTX + o];
      } else if (gi < PW_KT) {                // WbcT[o][c], stride 40
        int t = gi - PW_BC; int o = t / BCC, c = t % BCC;
        if (c < 20) v = Wbc[c*CTX + o];
      } else if (gi < PW_TGQ) {               // WkT[a][c], stride 72
        int t = gi - PW_KT; int a = t / KTC, c = t % KTC;
        if (c < 20)      v = Wk[(60 + c)*ATT + a];
        else if (c < 60) v = Wk[(80 + (c-20))*ATT + a];
      } else if (gi < PW_TGF) {               // WqTgT[j][c], stride 72
        int t = gi - PW_TGQ; int j = t / KTC, c = t % KTC;
        if (c < 64) v = Wq[(208 + c)*ATT + j];
      } else {                                // WffTgT[o][c], stride 72
        int t = gi - PW_TGF; int o = t / KTC, c = t % KTC;
        if (c < 64) v = Wff[(356 + c)*ALPHA + o];
      }
      pw[gi] = (fp16)v;
    }
  }
}

// ---------------- tags precompute: tag_q, tag_ff(+b_ff), 16 b per block ----------------
__global__ void dt_tags(const float* __restrict__ tags, const float* __restrict__ bff,
                        char* __restrict__ ws) {
  __shared__ fp16 wtq[ATT*KTC];     // 14.4 KB
  __shared__ fp16 wtf[ALPHA*KTC];   // 18.4 KB
  __shared__ fp16 tg[16*KTC];       // 2.3 KB
  __shared__ float bfl[ALPHA];
  const int tid = threadIdx.x, b0 = blockIdx.x*16;
  { const uint4* s = (const uint4*)((const fp16*)(ws + WS_W) + PW_TGQ);
    uint4* d = (uint4*)wtq; for (int i = tid; i < ATT*KTC*2/16; i += 256) d[i] = s[i]; }
  { const uint4* s = (const uint4*)((const fp16*)(ws + WS_W) + PW_TGF);
    uint4* d = (uint4*)wtf; for (int i = tid; i < ALPHA*KTC*2/16; i += 256) d[i] = s[i]; }
  for (int i = tid; i < 16*KTC; i += 256) {
    int bb = i / KTC, c = i % KTC;
    tg[i] = (c < 64) ? (fp16)tags[(size_t)(b0+bb)*64 + c] : (fp16)0.f;
  }
  if (tid < ALPHA) bfl[tid] = bff[tid];
  __syncthreads();
  fp16* tqw = (fp16*)(ws + WS_TQ);
  fp16* tfw = (fp16*)(ws + WS_TF);
  for (int t = tid; t < 16*228; t += 256) {
    int bb = t / 228, j = t % 228;
    const fp16* x = tg + bb*KTC;
    if (j < ATT) {
      float a = 0.f;
      const fp16* wv = wtq + j*KTC;
      #pragma unroll
      for (int k = 0; k < KTC/8; ++k)
        a = dot8f(*(const f16x8*)(x + 8*k), *(const f16x8*)(wv + 8*k), a);
      tqw[(size_t)(b0+bb)*ATT + j] = (fp16)a;
    } else {
      int o = j - ATT;
      float a = bfl[o];
      const fp16* wv = wtf + o*KTC;
      #pragma unroll
      for (int k = 0; k < KTC/8; ++k)
        a = dot8f(*(const f16x8*)(x + 8*k), *(const f16x8*)(wv + 8*k), a);
      tfw[(size_t)(b0+bb)*ALPHA + o] = (fp16)a;
    }
  }
}

// ---------------- encoder: ctxt ----------------
__global__ void dt_enc_ctxt(const int* __restrict__ lemma,
    const float* __restrict__ Wb4, const float* __restrict__ bb4,
    const float* __restrict__ Waft, const float* __restrict__ baft,
    const float* __restrict__ Wall, const float* __restrict__ ball,
    char* __restrict__ ws) {
  __shared__ float cet[ALPHA*CTX];
  __shared__ float wb4[40*20], wa[20*20], wl[40*20];
  __shared__ float bi4[20], biA[20], biL[20];
  const float* ceT = (const float*)(ws + WS_CE);
  const int tid = threadIdx.x;
  for (int i = tid; i < ALPHA*CTX; i += 256) cet[i] = ceT[i];
  for (int i = tid; i < 800; i += 256) wb4[i] = Wb4[i];
  for (int i = tid; i < 400; i += 256) wa[i] = Waft[i];
  for (int i = tid; i < 800; i += 256) wl[i] = Wall[i];
  if (tid < 20) { bi4[tid] = bb4[tid]; biA[tid] = baft[tid]; biL[tid] = ball[tid]; }
  __syncthreads();
  const int g = blockIdx.x*256 + tid;     // exactly 50*4096
  const int l = g / BB, b = g % BB;
  const int im2 = (l >= 2)    ? lemma[(l-2)*BB + b] : -1;
  const int im1 = (l >= 1)    ? lemma[(l-1)*BB + b] : -1;
  const int ip1 = (l < LL-1)  ? lemma[(l+1)*BB + b] : -1;
  float c2[CTX], c1[CTX], cf[CTX];
  #pragma unroll
  for (int c = 0; c < CTX; ++c) {
    c2[c] = (im2 >= 0) ? cet[im2*CTX + c] : 0.f;
    c1[c] = (im1 >= 0) ? cet[im1*CTX + c] : 0.f;
    cf[c] = (ip1 >= 0) ? cet[ip1*CTX + c] : 0.f;
  }
  float bv[CTX], av[CTX];
  #pragma unroll
  for (int o = 0; o < CTX; ++o) {
    float a = bi4[o];
    #pragma unroll
    for (int c = 0; c < CTX; ++c) a += c2[c]*wb4[c*CTX + o] + c1[c]*wb4[(CTX+c)*CTX + o];
    bv[o] = sigm(a);
  }
  #pragma unroll
  for (int o = 0; o < CTX; ++o) {
    float a = biA[o];
    #pragma unroll
    for (int c = 0; c < CTX; ++c) a += cf[c]*wa[c*CTX + o];
    av[o] = sigm(a);
  }
  float* ct = (float*)(ws + WS_CT);
  #pragma unroll
  for (int o = 0; o < CTX; ++o) {
    float a = biL[o];
    #pragma unroll
    for (int c = 0; c < CTX; ++c) a += bv[c]*wl[c*CTX + o] + av[c]*wl[(CTX+c)*CTX + o];
    ct[(size_t)g*CTX + o] = sigm(a);
  }
}

// ---------------- encoder: K (sigmoid keys, f16 dots) and V ----------------
__global__ void dt_enc_kv(const int* __restrict__ lemma, const float* __restrict__ embT,
                          char* __restrict__ ws) {
  __shared__ float ctl[LL*CTX];     // 4 KB
  __shared__ float eml[LL*EMB];     // 8 KB
  __shared__ fp16  xin[LL*64];      // 6.4 KB  (ctxt|emb|pad)
  __shared__ fp16  wkt[ATT*KTC];    // 14.4 KB
  __shared__ float pkl[LL*ATT];     // 20 KB
  __shared__ int lem[LL];
  const int b = blockIdx.x, tid = threadIdx.x;
  const float* ct = (const float*)(ws + WS_CT);
  if (tid < LL) lem[tid] = lemma[tid*BB + b];
  for (int i = tid; i < LL*CTX; i += 256) {
    int l = i / CTX; ctl[i] = ct[(size_t)(l*BB + b)*CTX + (i % CTX)];
  }
  { const uint4* s = (const uint4*)((const fp16*)(ws + WS_W) + PW_KT);
    uint4* d = (uint4*)wkt; for (int i = tid; i < ATT*KTC*2/16; i += 256) d[i] = s[i]; }
  { const float* s = (const float*)(ws + WS_PK);
    for (int i = tid; i < LL*ATT; i += 256) pkl[i] = s[i]; }
  __syncthreads();
  for (int i = tid; i < LL*EMB; i += 256) {
    int l = i / EMB; eml[i] = embT[lem[l]*EMB + (i % EMB)];
  }
  __syncthreads();
  for (int i = tid; i < LL*64; i += 256) {
    int l = i / 64, c = i % 64;
    float v = 0.f;
    if (c < 20) v = ctl[l*CTX + c];
    else if (c < 60) v = eml[l*EMB + (c-20)];
    xin[i] = (fp16)v;
  }
  __syncthreads();
  fp16* Kw = (fp16*)(ws + WS_K) + (size_t)b*K_ELE;
  for (int i = tid; i < K_ELE; i += 256) {
    int l = i / KP, a = i % KP;
    fp16 v = (fp16)0.f;
    if (a < ATT) {
      float acc = pkl[l*ATT + a];
      const fp16* x = xin + l*64;
      const fp16* wv = wkt + a*KTC;
      #pragma unroll
      for (int k = 0; k < 8; ++k)
        acc = dot8f(*(const f16x8*)(x + 8*k), *(const f16x8*)(wv + 8*k), acc);
      v = (fp16)sigm(acc);
    }
    Kw[i] = v;
  }
  fp16* Vw = (fp16*)(ws + WS_V) + (size_t)b*V_ELE;
  for (int i = tid; i < V_ELE; i += 256) {
    int d = i / VP, l = i % VP;
    float v = 0.f;
    if (l < LL) v = (d < CTX) ? ctl[l*CTX + d] : eml[l*EMB + (d - CTX)];
    Vw[i] = (fp16)v;
  }
}

// ---------------- decoder: 1 batch elem per wave, zero barriers in loop ----------------
__global__ __launch_bounds__(512, 2)
void dt_decoder(const char* __restrict__ ws, const float* __restrict__ b_re,
                const float* __restrict__ b_bc, float* __restrict__ out) {
  extern __shared__ char sm[];
  fp16*  wlds  = (fp16*)sm;
  float* posql = (float*)(sm + SM_PQ);
  const int tid = threadIdx.x, lane = tid & 63, w = tid >> 6;
  const int b = blockIdx.x*8 + w;
  fp16* my = (fp16*)(sm + SM_WV) + w*WV_STRIDE;
  fp16* xq = my + XQ_O;
  fp16* xf = my + XF_O;
  fp16* qv = my + Q_O;
  fp16* at = my + AT_O;
  fp16* rp = my + RPP_O;
  fp16* tq = my + TQ_O;
  fp16* tf = my + TF_O;

  // ---- stage shared (block-wide) ----
  { const uint4* s = (const uint4*)(ws + WS_W); uint4* d = (uint4*)sm;
    for (int i = tid; i < PW_DEC*2/16; i += 512) d[i] = s[i]; }
  { const uint* s = (const uint*)(ws + WS_PQ); uint* d = (uint*)posql;
    for (int i = tid; i < LL*ATT; i += 512) d[i] = s[i]; }

  // ---- per-wave state init ----
  for (int c = lane; c < QC;  c += 64) xq[c] = (fp16)0.f;
  for (int c = lane; c < FFC; c += 64) xf[c] = (fp16)0.f;
  for (int c = lane; c < 56;  c += 64) at[c] = (fp16)0.f;
  if (lane < 24) rp[lane] = (fp16)0.f;
  if (lane < 4)  qv[100 + lane] = (fp16)0.f;
  if (lane == 1) { xq[1] = (fp16)1.f; xf[1] = (fp16)1.f; }
  { const uint* s = (const uint*)(ws + WS_TQ + (size_t)b*ATT*2);
    if (lane < ATT/2) ((uint*)tq)[lane] = s[lane];
    if (lane < 2) ((uint*)tq)[ATT/2 + lane] = 0u; }
  { const uint* s = (const uint*)(ws + WS_TF + (size_t)b*ALPHA*2);
    ((uint*)tf)[lane] = s[lane]; }

  // ---- K/V into registers (lane l: K row l; lane d: V col d) ----
  f16x8 Kr[13];
  f16x4 Vr[13];
  { const fp16* kg = (const fp16*)(ws + WS_K) + (size_t)b*K_ELE + (lane < LL ? lane : LL-1)*KP;
    #pragma unroll
    for (int k = 0; k < 13; ++k) Kr[k] = *(const f16x8*)(kg + 8*k); }
  { const fp16* vg = (const fp16*)(ws + WS_V) + (size_t)b*V_ELE + (lane < 60 ? lane : 59)*VP;
    #pragma unroll
    for (int k = 0; k < 13; ++k) Vr[k] = *(const f16x4*)(vg + 4*k); }

  // out row 0 = one-hot start
  out[(size_t)b*ALPHA + lane]      = (lane == 1) ? 1.f : 0.f;
  out[(size_t)b*ALPHA + 64 + lane] = 0.f;

  const bool isC = (lane < CTX);
  const bool isR = (lane >= 32 && lane < 32 + CTX);
  const float bbc_r = isC ? b_bc[lane] : 0.f;
  const float bre_r = isR ? b_re[lane - 32] : 0.f;

  __syncthreads();

  for (int i = 1; i < LL; ++i) {
    // ---- P1: rnew = sig(probs@Wre) [lanes 32..51]; ctx = sig(rpp@Wbc) [lanes 0..19] ----
    float rnew = 0.f, ctxv = 0.f;
    if (isR) {
      const int o = lane - 32;
      const fp16* wr = wlds + PW_RE + o*REC;
      float a0 = bre_r, a1 = 0.f;
      #pragma unroll
      for (int k = 0; k < 16; k += 2) {
        a0 = dot8f(*(const f16x8*)(xq + 8*k),     *(const f16x8*)(wr + 8*k),     a0);
        a1 = dot8f(*(const f16x8*)(xq + 8*(k+1)), *(const f16x8*)(wr + 8*(k+1)), a1);
      }
      rnew = sigm(a0 + a1);
    }
    if (isC) {
      const fp16* wb = wlds + PW_BC + lane*BCC;
      float a = bbc_r;
      #pragma unroll
      for (int k = 0; k < 3; ++k)
        a = dot8f(*(const f16x8*)(rp + 8*k), *(const f16x8*)(wb + 8*k), a);
      ctxv = sigm(a);
    }
    if (isR) rp[lane - 32] = (fp16)rnew;
    if (isC) { xq[128 + lane] = (fp16)ctxv; xf[188 + lane] = (fp16)ctxv; }

    // ---- P2: q = sig(xq @ WqT), outputs lane and lane+64 ----
    {
      const int j2 = 64 + lane;
      const bool has2 = (j2 < ATT);
      const int j2c = has2 ? j2 : ATT-1;
      float a0 = posql[i*ATT + lane] + (float)tq[lane], a1 = 0.f;
      float b0 = posql[i*ATT + j2c]  + (float)tq[j2c],  b1 = 0.f;
      const fp16* w1 = wlds + PW_Q + lane*QC;
      const fp16* w2 = wlds + PW_Q + j2c*QC;
      #pragma unroll
      for (int k = 0; k < QC/8; ++k) {
        f16x8 x = *(const f16x8*)(xq + 8*k);
        if (k & 1) { a1 = dot8f(x, *(const f16x8*)(w1 + 8*k), a1);
                     b1 = dot8f(x, *(const f16x8*)(w2 + 8*k), b1); }
        else       { a0 = dot8f(x, *(const f16x8*)(w1 + 8*k), a0);
                     b0 = dot8f(x, *(const f16x8*)(w2 + 8*k), b0); }
      }
      qv[lane] = (fp16)sigm(a0 + a1);
      if (has2) qv[j2] = (fp16)sigm(b0 + b1);
    }

    // ---- P3: scores = q . K[lane], softmax over 50 ----
    {
      float a = 0.f;
      #pragma unroll
      for (int k = 0; k < 13; ++k)
        a = dot8f(*(const f16x8*)(qv + 8*k), Kr[k], a);
      float s = (lane < LL) ? a : -1e30f;
      float m  = wredmax(s);
      float e  = (lane < LL) ? __expf(s - m) : 0.f;
      float su = wredsum(e);
      if (lane < LL) at[lane] = (fp16)(e / su);
    }

    // ---- P4: in_attn[lane] = attn . V-col[lane] ----
    {
      float a = 0.f;
      #pragma unroll
      for (int k = 0; k < 13; ++k)
        a = dot4f(*(const f16x4*)(at + 4*k), Vr[k], a);
      if (lane < 60) xf[128 + lane] = (fp16)a;
    }

    // ---- P5: p = softmax(sig(xf @ WffT)), outputs lane and lane+64 ----
    {
      float a0 = (float)tf[lane],      a1 = 0.f;
      float b0 = (float)tf[64 + lane], b1 = 0.f;
      const fp16* w1 = wlds + PW_FF + lane*FFC;
      const fp16* w2 = wlds + PW_FF + (64 + lane)*FFC;
      #pragma unroll
      for (int k = 0; k < FFC/8; ++k) {
        f16x8 x = *(const f16x8*)(xf + 8*k);
        if (k & 1) { a1 = dot8f(x, *(const f16x8*)(w1 + 8*k), a1);
                     b1 = dot8f(x, *(const f16x8*)(w2 + 8*k), b1); }
        else       { a0 = dot8f(x, *(const f16x8*)(w1 + 8*k), a0);
                     b0 = dot8f(x, *(const f16x8*)(w2 + 8*k), b0); }
      }
      float sA = sigm(a0 + a1), sB = sigm(b0 + b1);
      float m  = wredmax(fmaxf(sA, sB));
      float eA = __expf(sA - m), eB = __expf(sB - m);
      float su = wredsum(eA + eB);
      float inv = 1.f / su;
      float pA = eA * inv, pB = eB * inv;
      out[((size_t)i*BB + b)*ALPHA + lane]      = pA;
      out[((size_t)i*BB + b)*ALPHA + 64 + lane] = pB;
      xq[lane] = (fp16)pA; xq[64 + lane] = (fp16)pB;
      xf[lane] = (fp16)pA; xf[64 + lane] = (fp16)pB;
    }
  }
}

extern "C" void kernel_launch(void* const* d_in, const int* in_sizes, int n_in,
                              void* d_out, int out_size, void* d_ws, size_t ws_size,
                              hipStream_t stream) {
  const int*   lemma = (const int*)  d_in[0];
  const float* tags  = (const float*)d_in[1];
  const float* embT  = (const float*)d_in[2];
  const float* Wce   = (const float*)d_in[3];
  const float* bce   = (const float*)d_in[4];
  const float* Wb4   = (const float*)d_in[5];
  const float* bb4   = (const float*)d_in[6];
  const float* Waft  = (const float*)d_in[7];
  const float* baft  = (const float*)d_in[8];
  const float* Wall  = (const float*)d_in[9];
  const float* ball  = (const float*)d_in[10];
  const float* Wre   = (const float*)d_in[11];
  const float* bre   = (const float*)d_in[12];
  const float* Wbc   = (const float*)d_in[13];
  const float* bbc   = (const float*)d_in[14];
  const float* Wq    = (const float*)d_in[15];
  const float* bq    = (const float*)d_in[16];
  const float* Wk    = (const float*)d_in[17];
  const float* bk    = (const float*)d_in[18];
  const float* Wff   = (const float*)d_in[19];
  const float* bff   = (const float*)d_in[20];
  char* ws = (char*)d_ws;
  float* out = (float*)d_out;

  hipFuncSetAttribute((const void*)dt_decoder,
                      hipFuncAttributeMaxDynamicSharedMemorySize, SM_TOT);

  dt_setup<<<64, 256, 0, stream>>>(embT, Wce, bce, Wq, bq, Wk, bk, Wff, Wre, Wbc, ws);
  dt_tags<<<BB/16, 256, 0, stream>>>(tags, bff, ws);
  dt_enc_ctxt<<<LL*BB/256, 256, 0, stream>>>(lemma, Wb4, bb4, Waft, baft, Wall, ball, ws);
  dt_enc_kv<<<BB, 256, 0, stream>>>(lemma, embT, ws);
  dt_decoder<<<BB/8, 512, SM_TOT, stream>>>(ws, bre, bbc, out);
}

// Round 3
// 608.572 us; speedup vs baseline: 2.8214x; 1.7273x over previous
//
#include <hip/hip_runtime.h>

using fp16 = _Float16;
typedef fp16 f16x4 __attribute__((ext_vector_type(4)));
typedef fp16 f16x8 __attribute__((ext_vector_type(8)));
typedef float f32x4 __attribute__((ext_vector_type(4)));

#define DEVI __device__ __forceinline__

constexpr int LL = 50;
constexpr int BB = 4096;
constexpr int ALPHA = 128;
constexpr int CTX = 20;
constexpr int ATT = 100;

// ---- fragment image element offsets (fp16 elems) ----
// frag linear layout: ((frag)*64 + lane)*8 + j ; frag = nt*KT + kt
constexpr int FQ_OFF  = 0;       // Wq_eff  [K=160][N=112]  NT=7 KT=5  (probs|ctx|pad)
constexpr int FF_OFF  = 17920;   // Wff_eff [K=224][N=128]  NT=8 KT=7  (probs|attn|ctx|pad)
constexpr int FR_OFF  = 46592;   // Wre     [K=128][N=32]   NT=2 KT=4
constexpr int FB_OFF  = 50688;   // Wbc     [K=32][N=32]    NT=2 KT=1
constexpr int FTQ_OFF = 51712;   // Wq tag rows [64][112]   NT=7 KT=2
constexpr int FTF_OFF = 58880;   // Wff tag rows[64][128]   NT=8 KT=2
constexpr int FRAG_TOT= 67072;

// ---- workspace byte offsets ----
constexpr size_t WS_FRAG = 0;                          // 134144 B
constexpr size_t WS_PQ   = 134144;                     // f32 [50][112] pos@Wq + bq
constexpr size_t WS_PK   = 156544;                     // f32 [50][112] pos@Wk + bk
constexpr size_t WS_CE   = 178944;                     // f16 [128][20] ce table
constexpr size_t WS_EM   = 184064;                     // f16 [128][40] emb table
constexpr size_t WS_WK   = 194304;                     // f16 [112][68] WkT (a-major)
constexpr size_t WS_K    = 209664;                     // f16 [4096][50][104]
constexpr size_t WS_V    = WS_K + (size_t)BB*5200*2;   // f16 [4096][60][52]
// end ~68.4 MB

// decoder LDS strides (f16 elems)
constexpr int XQS = 168;   // xq row (128 probs|20 ctx|zeros)   336B -> conflict-free
constexpr int XFS = 232;   // xf row (128 probs|60 attn|20 ctx|zeros)
constexpr int QBS = 120;   // q row
constexpr int SCS = 132;   // scores row (f32)

DEVI float sigm(float x) { return 1.0f / (1.0f + __expf(-x)); }

DEVI f32x4 mfma16(f16x8 a, f16x8 b, f32x4 c) {
  return __builtin_amdgcn_mfma_f32_16x16x32_f16(a, b, c, 0, 0, 0);
}

DEVI float dot8f(f16x8 a, f16x8 b, float acc) {
  acc = __builtin_amdgcn_fdot2(__builtin_shufflevector(a,a,0,1), __builtin_shufflevector(b,b,0,1), acc, false);
  acc = __builtin_amdgcn_fdot2(__builtin_shufflevector(a,a,2,3), __builtin_shufflevector(b,b,2,3), acc, false);
  acc = __builtin_amdgcn_fdot2(__builtin_shufflevector(a,a,4,5), __builtin_shufflevector(b,b,4,5), acc, false);
  acc = __builtin_amdgcn_fdot2(__builtin_shufflevector(a,a,6,7), __builtin_shufflevector(b,b,6,7), acc, false);
  return acc;
}
DEVI float dot4f(f16x4 a, f16x4 b, float acc) {
  acc = __builtin_amdgcn_fdot2(__builtin_shufflevector(a,a,0,1), __builtin_shufflevector(b,b,0,1), acc, false);
  acc = __builtin_amdgcn_fdot2(__builtin_shufflevector(a,a,2,3), __builtin_shufflevector(b,b,2,3), acc, false);
  return acc;
}
DEVI float wredmax(float v) {
  #pragma unroll
  for (int o = 32; o > 0; o >>= 1) v = fmaxf(v, __shfl_xor(v, o, 64));
  return v;
}
DEVI float wredsum(float v) {
  #pragma unroll
  for (int o = 32; o > 0; o >>= 1) v += __shfl_xor(v, o, 64);
  return v;
}

// ================= setup: tables + fragment-packed weights =================
__global__ void dt_setup(const float* __restrict__ embT, const float* __restrict__ Wce,
                         const float* __restrict__ bce,
                         const float* __restrict__ Wq, const float* __restrict__ bq,
                         const float* __restrict__ Wk, const float* __restrict__ bk,
                         const float* __restrict__ Wff, const float* __restrict__ Wre,
                         const float* __restrict__ Wbc, char* __restrict__ ws) {
  __shared__ float ap[LL*60];
  const int tid = threadIdx.x, bid = blockIdx.x;
  if (bid <= 1) {
    for (int i = tid; i < LL*30; i += 256) {
      int p = i / 30, k = i % 30;
      float freq = powf(10000.f, 2.0f*(float)k/60.0f);
      float ang = (float)p / freq;
      ap[p*60 + k]      = sinf(ang);
      ap[p*60 + 30 + k] = cosf(ang);
    }
    __syncthreads();
    const float* W = (bid == 0) ? Wq : Wk;
    const float* bi = (bid == 0) ? bq : bk;
    float* dst = (float*)(ws + (bid == 0 ? WS_PQ : WS_PK));
    for (int i = tid; i < LL*112; i += 256) {
      int r = i / 112, j = i % 112;
      float a = 0.f;
      if (j < ATT) {
        a = bi[j];
        for (int f = 0; f < 60; ++f) a += ap[r*60 + f]*W[f*ATT + j];
      }
      dst[i] = a;
    }
  } else if (bid == 2) {
    fp16* ce = (fp16*)(ws + WS_CE);
    for (int i = tid; i < ALPHA*CTX; i += 256) {
      int r = i / CTX, o = i % CTX;
      float a = bce[o];
      for (int e = 0; e < 40; ++e) a += embT[r*40 + e]*Wce[e*CTX + o];
      ce[i] = (fp16)a;
    }
    fp16* em = (fp16*)(ws + WS_EM);
    for (int i = tid; i < ALPHA*40; i += 256) em[i] = (fp16)embT[i];
  } else if (bid == 3) {
    fp16* wk = (fp16*)(ws + WS_WK);   // [112][68]: row a, col c
    for (int i = tid; i < 112*68; i += 256) {
      int a = i / 68, c = i % 68;
      float v = 0.f;
      if (a < ATT) {
        if (c < 20)      v = Wk[(60 + c)*ATT + a];
        else if (c < 60) v = Wk[(80 + (c-20))*ATT + a];
      }
      wk[i] = (fp16)v;
    }
  } else {
    fp16* pw = (fp16*)(ws + WS_FRAG);
    for (int gi = (bid-4)*256 + tid; gi < FRAG_TOT; gi += 28*256) {
      int t = gi, img, base, KT;
      if      (t < FF_OFF)  { img = 0; base = t - FQ_OFF;  KT = 5; }
      else if (t < FR_OFF)  { img = 1; base = t - FF_OFF;  KT = 7; }
      else if (t < FB_OFF)  { img = 2; base = t - FR_OFF;  KT = 4; }
      else if (t < FTQ_OFF) { img = 3; base = t - FB_OFF;  KT = 1; }
      else if (t < FTF_OFF) { img = 4; base = t - FTQ_OFF; KT = 2; }
      else                  { img = 5; base = t - FTF_OFF; KT = 2; }
      int j = base & 7, lane = (base >> 3) & 63, frag = base >> 9;
      int nt = frag / KT, kt = frag % KT;
      int k = kt*32 + ((lane >> 4) << 3) + j;
      int n = nt*16 + (lane & 15);
      float v = 0.f;
      if (img == 0) {
        if (n < ATT) {
          if (k < 128)      v = Wq[(80 + k)*ATT + n];
          else if (k < 148) v = Wq[(60 + (k - 128))*ATT + n];
        }
      } else if (img == 1) {
        if (k < 128)      v = Wff[(228 + k)*ALPHA + n];
        else if (k < 188) v = Wff[(k - 128)*ALPHA + n];
        else if (k < 208) v = Wff[(208 + (k - 188))*ALPHA + n];
      } else if (img == 2) {
        if (k < 128 && n < CTX) v = Wre[k*CTX + n];
      } else if (img == 3) {
        if (k < CTX && n < CTX) v = Wbc[k*CTX + n];
      } else if (img == 4) {
        if (n < ATT && k < 64)  v = Wq[(208 + k)*ATT + n];
      } else {
        if (k < 64)             v = Wff[(356 + k)*ALPHA + n];
      }
      pw[gi] = (fp16)v;
    }
  }
}

// ================= encode: ctxt + K + V, one batch elem per block =================
__global__ void dt_encode(const int* __restrict__ lemma,
    const float* __restrict__ Wb4, const float* __restrict__ bb4,
    const float* __restrict__ Waft, const float* __restrict__ baft,
    const float* __restrict__ Wall, const float* __restrict__ ball,
    char* __restrict__ ws) {
  __shared__ fp16 ce16l[ALPHA*CTX];
  __shared__ fp16 em16l[ALPHA*40];
  __shared__ fp16 wkl[112*68];
  __shared__ float wb4[800], wa[400], wl[800];
  __shared__ float cel[LL*CTX], b4l[LL*CTX], afl[LL*CTX];
  __shared__ fp16 xin[LL*68];
  __shared__ float bi4[CTX], biA[CTX], biL[CTX];
  __shared__ int lem[52];
  const int b = blockIdx.x, tid = threadIdx.x;

  { const fp16* s = (const fp16*)(ws + WS_CE);
    for (int i = tid; i < ALPHA*CTX; i += 256) ce16l[i] = s[i]; }
  { const fp16* s = (const fp16*)(ws + WS_EM);
    for (int i = tid; i < ALPHA*40; i += 256) em16l[i] = s[i]; }
  { const fp16* s = (const fp16*)(ws + WS_WK);
    for (int i = tid; i < 112*68; i += 256) wkl[i] = s[i]; }
  for (int i = tid; i < 800; i += 256) wb4[i] = Wb4[i];
  for (int i = tid; i < 400; i += 256) wa[i] = Waft[i];
  for (int i = tid; i < 800; i += 256) wl[i] = Wall[i];
  if (tid < CTX) { bi4[tid] = bb4[tid]; biA[tid] = baft[tid]; biL[tid] = ball[tid]; }
  if (tid < LL) lem[tid] = lemma[tid*BB + b];
  __syncthreads();

  for (int i = tid; i < LL*CTX; i += 256)
    cel[i] = (float)ce16l[lem[i/CTX]*CTX + (i % CTX)];
  __syncthreads();

  for (int i = tid; i < LL*CTX; i += 256) {
    int l = i / CTX, o = i % CTX;
    float a = bi4[o];
    for (int c = 0; c < CTX; ++c) {
      float c2 = (l >= 2) ? cel[(l-2)*CTX + c] : 0.f;
      float c1 = (l >= 1) ? cel[(l-1)*CTX + c] : 0.f;
      a += c2*wb4[c*CTX + o] + c1*wb4[(CTX+c)*CTX + o];
    }
    b4l[i] = sigm(a);
    float af = biA[o];
    if (l < LL-1)
      for (int c = 0; c < CTX; ++c) af += cel[(l+1)*CTX + c]*wa[c*CTX + o];
    afl[i] = sigm(af);
  }
  __syncthreads();

  for (int i = tid; i < LL*CTX; i += 256) {
    int l = i / CTX, o = i % CTX;
    float a = biL[o];
    for (int c = 0; c < CTX; ++c)
      a += b4l[l*CTX + c]*wl[c*CTX + o] + afl[l*CTX + c]*wl[(CTX+c)*CTX + o];
    xin[l*68 + o] = (fp16)sigm(a);
  }
  for (int i = tid; i < LL*40; i += 256) {
    int l = i / 40, d = i % 40;
    xin[l*68 + 20 + d] = em16l[lem[l]*40 + d];
  }
  for (int i = tid; i < LL*8; i += 256) {
    int l = i / 8, c = i % 8;
    xin[l*68 + 60 + c] = (fp16)0.f;
  }
  __syncthreads();

  const float* pkg = (const float*)(ws + WS_PK);
  fp16* Kw = (fp16*)(ws + WS_K) + (size_t)b*5200;
  for (int i = tid; i < 5200; i += 256) {
    int l = i / 104, a = i % 104;
    fp16 v = (fp16)0.f;
    if (a < ATT) {
      float acc = pkg[l*112 + a];
      const fp16* x = xin + l*68;
      const fp16* wv = wkl + a*68;
      #pragma unroll
      for (int k = 0; k < 16; ++k)
        acc = dot4f(*(const f16x4*)(x + 4*k), *(const f16x4*)(wv + 4*k), acc);
      v = (fp16)sigm(acc);
    }
    Kw[i] = v;
  }
  fp16* Vw = (fp16*)(ws + WS_V) + (size_t)b*3120;
  for (int i = tid; i < 3120; i += 256) {
    int d = i / 52, l = i % 52;
    Vw[i] = (l < LL) ? xin[l*68 + d] : (fp16)0.f;
  }
}

// ================= decoder: MFMA, weights in VGPRs, 8 elems/block =================
__global__ __launch_bounds__(512, 2)
void dt_decoder(const char* __restrict__ ws, const float* __restrict__ tags,
                const float* __restrict__ b_re, const float* __restrict__ b_bc,
                const float* __restrict__ bff, float* __restrict__ out) {
  __shared__ fp16 xq[16*XQS];
  __shared__ fp16 xf[16*XFS];
  __shared__ fp16 rp[2][16*40];
  __shared__ fp16 qb[16*QBS];
  __shared__ float sc[16*SCS];
  __shared__ fp16 atb[8*56];
  __shared__ float posql[LL*112];
  __shared__ float tagq[8*112];
  __shared__ float tagf[8*128];
  __shared__ fp16 tagsl[16*72];
  __shared__ float brel[32], bbcl[32];

  const int tid = threadIdx.x, lane = tid & 63, w = tid >> 6;
  const int b0 = blockIdx.x * 8;
  const int b = b0 + w;

  // ---- zero-init LDS state ----
  for (int i = tid; i < 16*XQS; i += 512) xq[i] = (fp16)0.f;
  for (int i = tid; i < 16*XFS; i += 512) xf[i] = (fp16)0.f;
  for (int i = tid; i < 2*16*40; i += 512) rp[0][i] = (fp16)0.f;
  for (int i = tid; i < 8*56; i += 512) atb[i] = (fp16)0.f;
  for (int i = tid; i < 16*72; i += 512) tagsl[i] = (fp16)0.f;
  { const float* s = (const float*)(ws + WS_PQ);
    for (int i = tid; i < LL*112; i += 512) posql[i] = s[i]; }
  if (tid < 32) { brel[tid] = (tid < CTX) ? b_re[tid] : 0.f;
                  bbcl[tid] = (tid < CTX) ? b_bc[tid] : 0.f; }
  for (int i = tid; i < 8*64; i += 512) {
    int e = i >> 6, c = i & 63;
    tagsl[e*72 + c] = (fp16)tags[(size_t)(b0 + e)*64 + c];
  }
  if (tid < 8) { xq[tid*XQS + 1] = (fp16)1.f; xf[tid*XFS + 1] = (fp16)1.f; }
  for (int i = tid; i < 1024; i += 512) {
    int e = i >> 7, o = i & 127;
    out[(size_t)(b0 + e)*ALPHA + o] = (o == 1) ? 1.f : 0.f;
  }

  // ---- weight fragments into VGPRs ----
  const fp16* fw = (const fp16*)(ws + WS_FRAG);
  f16x8 wA[8], wB[7], wC[2], wD[2];
  if (w < 7) {
    #pragma unroll
    for (int kt = 0; kt < 5; ++kt)
      wA[kt] = *(const f16x8*)(fw + FQ_OFF + (((w*5 + kt) << 6) + lane)*8);
    #pragma unroll
    for (int kt = 0; kt < 2; ++kt)
      wC[kt] = *(const f16x8*)(fw + FTQ_OFF + (((w*2 + kt) << 6) + lane)*8);
  } else {
    #pragma unroll
    for (int t = 0; t < 8; ++t)
      wA[t] = *(const f16x8*)(fw + FR_OFF + ((t << 6) + lane)*8);
    #pragma unroll
    for (int t = 0; t < 2; ++t)
      wC[t] = *(const f16x8*)(fw + FB_OFF + ((t << 6) + lane)*8);
  }
  #pragma unroll
  for (int kt = 0; kt < 7; ++kt)
    wB[kt] = *(const f16x8*)(fw + FF_OFF + (((w*7 + kt) << 6) + lane)*8);
  #pragma unroll
  for (int kt = 0; kt < 2; ++kt)
    wD[kt] = *(const f16x8*)(fw + FTF_OFF + (((w*2 + kt) << 6) + lane)*8);

  // ---- K/V into registers ----
  f16x8 Kr[12]; f16x4 Kr12; f16x4 Vr[13];
  { const fp16* kg = (const fp16*)(ws + WS_K) + (size_t)b*5200 + (lane < LL ? lane : LL-1)*104;
    #pragma unroll
    for (int k = 0; k < 12; ++k) Kr[k] = *(const f16x8*)(kg + 8*k);
    Kr12 = *(const f16x4*)(kg + 96); }
  { const fp16* vg = (const fp16*)(ws + WS_V) + (size_t)b*3120 + (lane < 60 ? lane : 59)*52;
    #pragma unroll
    for (int k = 0; k < 13; ++k) Vr[k] = *(const f16x4*)(vg + 4*k); }

  const float bffr = bff[w*16 + (lane & 15)];
  __syncthreads();

  // ---- tag projections via MFMA ----
  {
    const int arow = lane & 15, koff = (lane >> 4)*8;
    f16x8 a0 = *(const f16x8*)(tagsl + arow*72 + koff);
    f16x8 a1 = *(const f16x8*)(tagsl + arow*72 + 32 + koff);
    const int r0 = (lane >> 4)*4, colg = w*16 + (lane & 15);
    if (w < 7) {
      f32x4 c = {0.f,0.f,0.f,0.f};
      c = mfma16(a0, wC[0], c); c = mfma16(a1, wC[1], c);
      #pragma unroll
      for (int r = 0; r < 4; ++r) { int rr = r0 + r; if (rr < 8) tagq[rr*112 + colg] = c[r]; }
    }
    f32x4 d = {0.f,0.f,0.f,0.f};
    d = mfma16(a0, wD[0], d); d = mfma16(a1, wD[1], d);
    #pragma unroll
    for (int r = 0; r < 4; ++r) { int rr = r0 + r; if (rr < 8) tagf[rr*128 + colg] = d[r] + bffr; }
  }
  __syncthreads();

  // ==================== recurrence ====================
  for (int i = 1; i < LL; ++i) {
    // ---- A1 (wave 7): rnew = sig(probs@Wre+bre); ctx = sig(rp@Wbc+bbc) ----
    if (w == 7) {
      const fp16* rpr = rp[(i-1) & 1];
      const int arow = lane & 15, koff = (lane >> 4)*8;
      f32x4 c0 = {0.f,0.f,0.f,0.f}, c1 = {0.f,0.f,0.f,0.f};
      #pragma unroll
      for (int kt = 0; kt < 4; ++kt) {
        f16x8 a = *(const f16x8*)(xq + arow*XQS + kt*32 + koff);
        c0 = mfma16(a, wA[kt],     c0);
        c1 = mfma16(a, wA[4 + kt], c1);
      }
      f16x8 ar = *(const f16x8*)(rpr + arow*40 + koff);
      f32x4 d0 = {0.f,0.f,0.f,0.f}, d1 = {0.f,0.f,0.f,0.f};
      d0 = mfma16(ar, wC[0], d0);
      d1 = mfma16(ar, wC[1], d1);
      fp16* rpw = rp[i & 1];
      const int r0 = (lane >> 4)*4, cA = lane & 15, cB = 16 + (lane & 15);
      #pragma unroll
      for (int r = 0; r < 4; ++r) {
        int rr = r0 + r;
        if (rr < 8) {
          if (cA < CTX) {
            rpw[rr*40 + cA] = (fp16)sigm(c0[r] + brel[cA]);
            float cv = sigm(d0[r] + bbcl[cA]);
            xq[rr*XQS + 128 + cA] = (fp16)cv;
            xf[rr*XFS + 188 + cA] = (fp16)cv;
          }
          if (cB < CTX) {
            rpw[rr*40 + cB] = (fp16)sigm(c1[r] + brel[cB]);
            float cv = sigm(d1[r] + bbcl[cB]);
            xq[rr*XQS + 128 + cB] = (fp16)cv;
            xf[rr*XFS + 188 + cB] = (fp16)cv;
          }
        }
      }
    }
    __syncthreads();

    // ---- A2 (waves 0-6): q = sig(xq@Wq + pos + tagq) ----
    if (w < 7) {
      const int arow = lane & 15, koff = (lane >> 4)*8;
      f32x4 c = {0.f,0.f,0.f,0.f};
      #pragma unroll
      for (int kt = 0; kt < 5; ++kt)
        c = mfma16(*(const f16x8*)(xq + arow*XQS + kt*32 + koff), wA[kt], c);
      const int r0 = (lane >> 4)*4, colg = w*16 + (lane & 15);
      #pragma unroll
      for (int r = 0; r < 4; ++r) {
        int rr = r0 + r;
        if (rr < 8)
          qb[rr*QBS + colg] = (fp16)sigm(c[r] + posql[i*112 + colg] + tagq[rr*112 + colg]);
      }
    }
    __syncthreads();

    // ---- P34 (wave e=w): scores, softmax, in_attn ----
    {
      const fp16* qrow = qb + w*QBS;
      float a0 = 0.f, a1 = 0.f;
      #pragma unroll
      for (int k = 0; k < 12; k += 2) {
        a0 = dot8f(*(const f16x8*)(qrow + 8*k),     Kr[k],   a0);
        a1 = dot8f(*(const f16x8*)(qrow + 8*(k+1)), Kr[k+1], a1);
      }
      a0 = dot4f(*(const f16x4*)(qrow + 96), Kr12, a0);
      float s = (lane < LL) ? (a0 + a1) : -1e30f;
      float m  = wredmax(s);
      float e  = (lane < LL) ? __expf(s - m) : 0.f;
      float su = wredsum(e);
      if (lane < LL) atb[w*56 + lane] = (fp16)(e / su);
      const fp16* ar = atb + w*56;
      float v0 = 0.f, v1 = 0.f;
      #pragma unroll
      for (int k = 0; k < 12; k += 2) {
        v0 = dot4f(*(const f16x4*)(ar + 4*k),     Vr[k],   v0);
        v1 = dot4f(*(const f16x4*)(ar + 4*(k+1)), Vr[k+1], v1);
      }
      v0 = dot4f(*(const f16x4*)(ar + 48), Vr[12], v0);
      if (lane < 60) xf[w*XFS + 128 + lane] = (fp16)(v0 + v1);
    }
    __syncthreads();

    // ---- P5 (all waves): s = sig(xf@Wff + tagf) ----
    {
      const int arow = lane & 15, koff = (lane >> 4)*8;
      f32x4 c = {0.f,0.f,0.f,0.f};
      #pragma unroll
      for (int kt = 0; kt < 7; ++kt)
        c = mfma16(*(const f16x8*)(xf + arow*XFS + kt*32 + koff), wB[kt], c);
      const int r0 = (lane >> 4)*4, colg = w*16 + (lane & 15);
      #pragma unroll
      for (int r = 0; r < 4; ++r) {
        int rr = r0 + r;
        if (rr < 8)
          sc[rr*SCS + colg] = sigm(c[r] + tagf[rr*128 + colg]);
      }
    }
    __syncthreads();

    // ---- P6 (wave e=w): softmax over 128, write out + probs ----
    {
      float v0 = sc[w*SCS + lane], v1 = sc[w*SCS + 64 + lane];
      float m = wredmax(fmaxf(v0, v1));
      float e0 = __expf(v0 - m), e1 = __expf(v1 - m);
      float su = wredsum(e0 + e1);
      float inv = 1.f / su;
      float p0 = e0*inv, p1 = e1*inv;
      size_t ob = ((size_t)i*BB + b)*ALPHA;
      out[ob + lane] = p0; out[ob + 64 + lane] = p1;
      xq[w*XQS + lane] = (fp16)p0; xq[w*XQS + 64 + lane] = (fp16)p1;
      xf[w*XFS + lane] = (fp16)p0; xf[w*XFS + 64 + lane] = (fp16)p1;
    }
    __syncthreads();
  }
}

extern "C" void kernel_launch(void* const* d_in, const int* in_sizes, int n_in,
                              void* d_out, int out_size, void* d_ws, size_t ws_size,
                              hipStream_t stream) {
  const int*   lemma = (const int*)  d_in[0];
  const float* tags  = (const float*)d_in[1];
  const float* embT  = (const float*)d_in[2];
  const float* Wce   = (const float*)d_in[3];
  const float* bce   = (const float*)d_in[4];
  const float* Wb4   = (const float*)d_in[5];
  const float* bb4   = (const float*)d_in[6];
  const float* Waft  = (const float*)d_in[7];
  const float* baft  = (const float*)d_in[8];
  const float* Wall  = (const float*)d_in[9];
  const float* ball  = (const float*)d_in[10];
  const float* Wre   = (const float*)d_in[11];
  const float* bre   = (const float*)d_in[12];
  const float* Wbc   = (const float*)d_in[13];
  const float* bbc   = (const float*)d_in[14];
  const float* Wq    = (const float*)d_in[15];
  const float* bq    = (const float*)d_in[16];
  const float* Wk    = (const float*)d_in[17];
  const float* bk    = (const float*)d_in[18];
  const float* Wff   = (const float*)d_in[19];
  const float* bff   = (const float*)d_in[20];
  char* ws = (char*)d_ws;
  float* out = (float*)d_out;

  dt_setup<<<32, 256, 0, stream>>>(embT, Wce, bce, Wq, bq, Wk, bk, Wff, Wre, Wbc, ws);
  dt_encode<<<BB, 256, 0, stream>>>(lemma, Wb4, bb4, Waft, baft, Wall, ball, ws);
  dt_decoder<<<BB/8, 512, 0, stream>>>(ws, tags, bre, bbc, bff, out);
}

// Round 4
// 458.813 us; speedup vs baseline: 3.7423x; 1.3264x over previous
//
#include <hip/hip_runtime.h>

using fp16 = _Float16;
typedef fp16 f16x4 __attribute__((ext_vector_type(4)));
typedef fp16 f16x8 __attribute__((ext_vector_type(8)));
typedef float f32x4 __attribute__((ext_vector_type(4)));

#define DEVI __device__ __forceinline__

constexpr int LL = 50;
constexpr int BB = 4096;
constexpr int ALPHA = 128;
constexpr int CTX = 20;
constexpr int ATT = 100;

// ---- fragment image element offsets (fp16 elems) ----
// frag linear layout: ((frag)*64 + lane)*8 + j ; frag = nt*KT + kt
constexpr int FQ_OFF  = 0;       // Wq_eff  [K=160][N=112]  NT=7 KT=5  (probs|ctx|pad)
constexpr int FF_OFF  = 17920;   // Wff_eff [K=224][N=128]  NT=8 KT=7  (probs|attn|ctx|pad)
constexpr int FR_OFF  = 46592;   // Wre     [K=128][N=32]   NT=2 KT=4
constexpr int FB_OFF  = 50688;   // Wbc     [K=32][N=32]    NT=2 KT=1
constexpr int FTQ_OFF = 51712;   // Wq tag rows [64][112]   NT=7 KT=2
constexpr int FTF_OFF = 58880;   // Wff tag rows[64][128]   NT=8 KT=2
constexpr int FRAG_TOT= 67072;

// ---- workspace byte offsets ----
constexpr size_t WS_FRAG = 0;                          // 134144 B
constexpr size_t WS_PQ   = 134144;                     // f32 [50][112] pos@Wq + bq
constexpr size_t WS_PK   = 156544;                     // f32 [50][112] pos@Wk + bk
constexpr size_t WS_TBL  = 178944;                     // f16 packed: ce[128*20] | em[128*40] | wk[112*72]
constexpr int    TBL_CE  = 0;
constexpr int    TBL_EM  = 2560;
constexpr int    TBL_WK  = 7680;
constexpr int    TBL_N   = 15744;                      // f16 elems (31488 B)
constexpr size_t WS_K    = 210432;                     // f16 [4096][50][104]
constexpr size_t WS_V    = WS_K + (size_t)BB*5200*2;   // f16 [4096][60][52]

// decoder LDS strides (f16 / f32 elems)
constexpr int XQS = 168;
constexpr int XFS = 232;
constexpr int QBS = 120;
constexpr int SCS = 132;   // f32

DEVI float rcpf(float x) { return __builtin_amdgcn_rcpf(x); }
DEVI float sigm(float x) { return rcpf(1.0f + __expf(-x)); }

DEVI f32x4 mfma16(f16x8 a, f16x8 b, f32x4 c) {
  return __builtin_amdgcn_mfma_f32_16x16x32_f16(a, b, c, 0, 0, 0);
}

DEVI float dot8f(f16x8 a, f16x8 b, float acc) {
  acc = __builtin_amdgcn_fdot2(__builtin_shufflevector(a,a,0,1), __builtin_shufflevector(b,b,0,1), acc, false);
  acc = __builtin_amdgcn_fdot2(__builtin_shufflevector(a,a,2,3), __builtin_shufflevector(b,b,2,3), acc, false);
  acc = __builtin_amdgcn_fdot2(__builtin_shufflevector(a,a,4,5), __builtin_shufflevector(b,b,4,5), acc, false);
  acc = __builtin_amdgcn_fdot2(__builtin_shufflevector(a,a,6,7), __builtin_shufflevector(b,b,6,7), acc, false);
  return acc;
}
DEVI float dot4f(f16x4 a, f16x4 b, float acc) {
  acc = __builtin_amdgcn_fdot2(__builtin_shufflevector(a,a,0,1), __builtin_shufflevector(b,b,0,1), acc, false);
  acc = __builtin_amdgcn_fdot2(__builtin_shufflevector(a,a,2,3), __builtin_shufflevector(b,b,2,3), acc, false);
  return acc;
}

// DPP all-VALU wave64 reductions. REQUIRES v >= 0 in all lanes (0-fill safe).
// row_shr:1/2/4/8 then row_bcast:15/31 -> lane 63 holds total -> readlane.
#define DPP_STEP(OP, CTRL)                                                        \
  { int t_ = __builtin_amdgcn_update_dpp(0, __builtin_bit_cast(int, v), CTRL, 0xF, 0xF, true); \
    v = OP(v, __builtin_bit_cast(float, t_)); }

DEVI float addf(float a, float b) { return a + b; }

DEVI float redmax64(float v) {
  DPP_STEP(fmaxf, 0x111) DPP_STEP(fmaxf, 0x112) DPP_STEP(fmaxf, 0x114)
  DPP_STEP(fmaxf, 0x118) DPP_STEP(fmaxf, 0x142) DPP_STEP(fmaxf, 0x143)
  return __builtin_bit_cast(float, __builtin_amdgcn_readlane(__builtin_bit_cast(int, v), 63));
}
DEVI float redsum64(float v) {
  DPP_STEP(addf, 0x111) DPP_STEP(addf, 0x112) DPP_STEP(addf, 0x114)
  DPP_STEP(addf, 0x118) DPP_STEP(addf, 0x142) DPP_STEP(addf, 0x143)
  return __builtin_bit_cast(float, __builtin_amdgcn_readlane(__builtin_bit_cast(int, v), 63));
}

// ================= setup: tables + fragment-packed weights =================
__global__ void dt_setup(const float* __restrict__ embT, const float* __restrict__ Wce,
                         const float* __restrict__ bce,
                         const float* __restrict__ Wq, const float* __restrict__ bq,
                         const float* __restrict__ Wk, const float* __restrict__ bk,
                         const float* __restrict__ Wff, const float* __restrict__ Wre,
                         const float* __restrict__ Wbc, char* __restrict__ ws) {
  __shared__ float ap[LL*60];
  const int tid = threadIdx.x, bid = blockIdx.x;
  if (bid <= 1) {
    for (int i = tid; i < LL*30; i += 256) {
      int p = i / 30, k = i % 30;
      float freq = powf(10000.f, 2.0f*(float)k/60.0f);
      float ang = (float)p / freq;
      ap[p*60 + k]      = sinf(ang);
      ap[p*60 + 30 + k] = cosf(ang);
    }
    __syncthreads();
    const float* W = (bid == 0) ? Wq : Wk;
    const float* bi = (bid == 0) ? bq : bk;
    float* dst = (float*)(ws + (bid == 0 ? WS_PQ : WS_PK));
    for (int i = tid; i < LL*112; i += 256) {
      int r = i / 112, j = i % 112;
      float a = 0.f;
      if (j < ATT) {
        a = bi[j];
        for (int f = 0; f < 60; ++f) a += ap[r*60 + f]*W[f*ATT + j];
      }
      dst[i] = a;
    }
  } else if (bid == 2) {
    fp16* tbl = (fp16*)(ws + WS_TBL);
    for (int i = tid; i < ALPHA*CTX; i += 256) {
      int r = i / CTX, o = i % CTX;
      float a = bce[o];
      for (int e = 0; e < 40; ++e) a += embT[r*40 + e]*Wce[e*CTX + o];
      tbl[TBL_CE + i] = (fp16)a;
    }
    for (int i = tid; i < ALPHA*40; i += 256) tbl[TBL_EM + i] = (fp16)embT[i];
  } else if (bid == 3) {
    fp16* tbl = (fp16*)(ws + WS_TBL);
    for (int i = tid; i < 112*72; i += 256) {
      int a = i / 72, c = i % 72;
      float v = 0.f;
      if (a < ATT) {
        if (c < 20)      v = Wk[(60 + c)*ATT + a];
        else if (c < 60) v = Wk[(80 + (c-20))*ATT + a];
      }
      tbl[TBL_WK + i] = (fp16)v;
    }
  } else {
    fp16* pw = (fp16*)(ws + WS_FRAG);
    for (int gi = (bid-4)*256 + tid; gi < FRAG_TOT; gi += 28*256) {
      int t = gi, img, base, KT;
      if      (t < FF_OFF)  { img = 0; base = t - FQ_OFF;  KT = 5; }
      else if (t < FR_OFF)  { img = 1; base = t - FF_OFF;  KT = 7; }
      else if (t < FB_OFF)  { img = 2; base = t - FR_OFF;  KT = 4; }
      else if (t < FTQ_OFF) { img = 3; base = t - FB_OFF;  KT = 1; }
      else if (t < FTF_OFF) { img = 4; base = t - FTQ_OFF; KT = 2; }
      else                  { img = 5; base = t - FTF_OFF; KT = 2; }
      int j = base & 7, lane = (base >> 3) & 63, frag = base >> 9;
      int nt = frag / KT, kt = frag % KT;
      int k = kt*32 + ((lane >> 4) << 3) + j;
      int n = nt*16 + (lane & 15);
      float v = 0.f;
      if (img == 0) {
        if (n < ATT) {
          if (k < 128)      v = Wq[(80 + k)*ATT + n];
          else if (k < 148) v = Wq[(60 + (k - 128))*ATT + n];
        }
      } else if (img == 1) {
        if (k < 128)      v = Wff[(228 + k)*ALPHA + n];
        else if (k < 188) v = Wff[(k - 128)*ALPHA + n];
        else if (k < 208) v = Wff[(208 + (k - 188))*ALPHA + n];
      } else if (img == 2) {
        if (k < 128 && n < CTX) v = Wre[k*CTX + n];
      } else if (img == 3) {
        if (k < CTX && n < CTX) v = Wbc[k*CTX + n];
      } else if (img == 4) {
        if (n < ATT && k < 64)  v = Wq[(208 + k)*ATT + n];
      } else {
        if (k < 64)             v = Wff[(356 + k)*ALPHA + n];
      }
      pw[gi] = (fp16)v;
    }
  }
}

// ================= encode: ctxt + K + V, one batch elem per block =================
__global__ void dt_encode(const int* __restrict__ lemma,
    const float* __restrict__ Wb4, const float* __restrict__ bb4,
    const float* __restrict__ Waft, const float* __restrict__ baft,
    const float* __restrict__ Wall, const float* __restrict__ ball,
    char* __restrict__ ws) {
  __shared__ fp16 tbl[TBL_N];           // ce | em | wk  (31.5 KB)
  __shared__ float wb4[800], wa[400], wl[800];
  __shared__ float cel[LL*CTX], b4l[LL*CTX], afl[LL*CTX];
  __shared__ fp16 xin[LL*72];
  __shared__ float bi4[CTX], biA[CTX], biL[CTX];
  __shared__ int lem[52];
  const int b = blockIdx.x, tid = threadIdx.x;

  { const uint4* s = (const uint4*)(ws + WS_TBL); uint4* d = (uint4*)tbl;
    for (int i = tid; i < TBL_N*2/16; i += 256) d[i] = s[i]; }
  { const float4* s = (const float4*)Wb4; float4* d = (float4*)wb4;
    for (int i = tid; i < 200; i += 256) d[i] = s[i]; }
  { const float4* s = (const float4*)Waft; float4* d = (float4*)wa;
    for (int i = tid; i < 100; i += 256) d[i] = s[i]; }
  { const float4* s = (const float4*)Wall; float4* d = (float4*)wl;
    for (int i = tid; i < 200; i += 256) d[i] = s[i]; }
  if (tid < CTX) { bi4[tid] = bb4[tid]; biA[tid] = baft[tid]; biL[tid] = ball[tid]; }
  if (tid < LL) lem[tid] = lemma[tid*BB + b];
  __syncthreads();

  for (int i = tid; i < LL*CTX; i += 256)
    cel[i] = (float)tbl[TBL_CE + lem[i/CTX]*CTX + (i % CTX)];
  __syncthreads();

  for (int i = tid; i < LL*CTX; i += 256) {
    int l = i / CTX, o = i % CTX;
    float a = bi4[o];
    for (int c = 0; c < CTX; ++c) {
      float c2 = (l >= 2) ? cel[(l-2)*CTX + c] : 0.f;
      float c1 = (l >= 1) ? cel[(l-1)*CTX + c] : 0.f;
      a += c2*wb4[c*CTX + o] + c1*wb4[(CTX+c)*CTX + o];
    }
    b4l[i] = sigm(a);
    float af = biA[o];
    if (l < LL-1)
      for (int c = 0; c < CTX; ++c) af += cel[(l+1)*CTX + c]*wa[c*CTX + o];
    afl[i] = sigm(af);
  }
  __syncthreads();

  for (int i = tid; i < LL*CTX; i += 256) {
    int l = i / CTX, o = i % CTX;
    float a = biL[o];
    for (int c = 0; c < CTX; ++c)
      a += b4l[l*CTX + c]*wl[c*CTX + o] + afl[l*CTX + c]*wl[(CTX+c)*CTX + o];
    xin[l*72 + o] = (fp16)sigm(a);
  }
  for (int i = tid; i < LL*40; i += 256) {
    int l = i / 40, d = i % 40;
    xin[l*72 + 20 + d] = tbl[TBL_EM + lem[l]*40 + d];
  }
  for (int i = tid; i < LL*12; i += 256) {
    int l = i / 12, c = i % 12;
    xin[l*72 + 60 + c] = (fp16)0.f;
  }
  __syncthreads();

  const float* pkg = (const float*)(ws + WS_PK);
  fp16* Kw = (fp16*)(ws + WS_K) + (size_t)b*5200;
  for (int i = tid; i < 5200; i += 256) {
    int l = i / 104, a = i % 104;
    fp16 v = (fp16)0.f;
    if (a < ATT) {
      float acc = pkg[l*112 + a];
      const fp16* x = xin + l*72;
      const fp16* wv = tbl + TBL_WK + a*72;
      #pragma unroll
      for (int k = 0; k < 9; ++k)
        acc = dot8f(*(const f16x8*)(x + 8*k), *(const f16x8*)(wv + 8*k), acc);
      v = (fp16)sigm(acc);
    }
    Kw[i] = v;
  }
  fp16* Vw = (fp16*)(ws + WS_V) + (size_t)b*3120;
  for (int i = tid; i < 3120; i += 256) {
    int d = i / 52, l = i % 52;
    Vw[i] = (l < LL) ? xin[l*72 + d] : (fp16)0.f;
  }
}

// ================= decoder: MFMA weights in VGPRs, DPP softmax, 4 barriers/step ===========
__global__ __launch_bounds__(512, 2)
void dt_decoder(const char* __restrict__ ws, const float* __restrict__ tags,
                const float* __restrict__ Wre, const float* __restrict__ b_re,
                const float* __restrict__ b_bc, const float* __restrict__ bff,
                float* __restrict__ out) {
  __shared__ fp16 xq[16*XQS];
  __shared__ fp16 xf[16*XFS];
  __shared__ fp16 rp[16*40];
  __shared__ fp16 qb[16*QBS];
  __shared__ float sc[16*SCS];
  __shared__ fp16 atb[8*56];
  __shared__ float posql[LL*112];
  __shared__ float tagq[8*112];
  __shared__ float tagf[8*128];
  __shared__ fp16 tagsl[16*72];
  __shared__ float brel[32], bbcl[32];

  const int tid = threadIdx.x, lane = tid & 63, w = tid >> 6;
  const int b0 = blockIdx.x * 8;
  const int b = b0 + w;

  // ---- zero-init LDS state ----
  for (int i = tid; i < 16*XQS; i += 512) xq[i] = (fp16)0.f;
  for (int i = tid; i < 16*XFS; i += 512) xf[i] = (fp16)0.f;
  for (int i = tid; i < 16*40; i += 512) rp[i] = (fp16)0.f;
  for (int i = tid; i < 8*56; i += 512) atb[i] = (fp16)0.f;
  for (int i = tid; i < 16*72; i += 512) tagsl[i] = (fp16)0.f;
  { const float* s = (const float*)(ws + WS_PQ);
    for (int i = tid; i < LL*112; i += 512) posql[i] = s[i]; }
  if (tid < 32) { brel[tid] = (tid < CTX) ? b_re[tid] : 0.f;
                  bbcl[tid] = (tid < CTX) ? b_bc[tid] : 0.f; }
  for (int i = tid; i < 8*64; i += 512) {
    int e = i >> 6, c = i & 63;
    tagsl[e*72 + c] = (fp16)tags[(size_t)(b0 + e)*64 + c];
  }
  if (tid < 8) { xq[tid*XQS + 1] = (fp16)1.f; xf[tid*XFS + 1] = (fp16)1.f; }
  // ctx(1) = sigm(b_bc) ; r[0] = sigm(Wre[1,:] + b_re)
  if (tid < 160) {
    int e = tid / CTX, o = tid % CTX;
    float c1 = sigm(b_bc[o]);
    xq[e*XQS + 128 + o] = (fp16)c1;
    xf[e*XFS + 188 + o] = (fp16)c1;
    rp[e*40 + o] = (fp16)sigm(Wre[CTX + o] + b_re[o]);
  }
  for (int i = tid; i < 1024; i += 512) {
    int e = i >> 7, o = i & 127;
    out[(size_t)(b0 + e)*ALPHA + o] = (o == 1) ? 1.f : 0.f;
  }

  // ---- weight fragments into VGPRs/AGPRs ----
  const fp16* fw = (const fp16*)(ws + WS_FRAG);
  f16x8 wA[8], wB[7], wC[2], wD[2];
  if (w < 7) {
    #pragma unroll
    for (int kt = 0; kt < 5; ++kt)
      wA[kt] = *(const f16x8*)(fw + FQ_OFF + (((w*5 + kt) << 6) + lane)*8);
    #pragma unroll
    for (int kt = 0; kt < 2; ++kt)
      wC[kt] = *(const f16x8*)(fw + FTQ_OFF + (((w*2 + kt) << 6) + lane)*8);
  } else {
    #pragma unroll
    for (int t = 0; t < 8; ++t)
      wA[t] = *(const f16x8*)(fw + FR_OFF + ((t << 6) + lane)*8);
    #pragma unroll
    for (int t = 0; t < 2; ++t)
      wC[t] = *(const f16x8*)(fw + FB_OFF + ((t << 6) + lane)*8);
  }
  #pragma unroll
  for (int kt = 0; kt < 7; ++kt)
    wB[kt] = *(const f16x8*)(fw + FF_OFF + (((w*7 + kt) << 6) + lane)*8);
  #pragma unroll
  for (int kt = 0; kt < 2; ++kt)
    wD[kt] = *(const f16x8*)(fw + FTF_OFF + (((w*2 + kt) << 6) + lane)*8);

  // ---- K/V into registers ----
  f16x8 Kr[12]; f16x4 Kr12; f16x4 Vr[13];
  { const fp16* kg = (const fp16*)(ws + WS_K) + (size_t)b*5200 + (lane < LL ? lane : LL-1)*104;
    #pragma unroll
    for (int k = 0; k < 12; ++k) Kr[k] = *(const f16x8*)(kg + 8*k);
    Kr12 = *(const f16x4*)(kg + 96); }
  { const fp16* vg = (const fp16*)(ws + WS_V) + (size_t)b*3120 + (lane < 60 ? lane : 59)*52;
    #pragma unroll
    for (int k = 0; k < 13; ++k) Vr[k] = *(const f16x4*)(vg + 4*k); }

  const float bffr = bff[w*16 + (lane & 15)];
  __syncthreads();

  // ---- tag projections via MFMA ----
  {
    const int arow = lane & 15, koff = (lane >> 4)*8;
    f16x8 a0 = *(const f16x8*)(tagsl + arow*72 + koff);
    f16x8 a1 = *(const f16x8*)(tagsl + arow*72 + 32 + koff);
    const int r0 = (lane >> 4)*4, colg = w*16 + (lane & 15);
    if (w < 7) {
      f32x4 c = {0.f,0.f,0.f,0.f};
      c = mfma16(a0, wC[0], c); c = mfma16(a1, wC[1], c);
      #pragma unroll
      for (int r = 0; r < 4; ++r) { int rr = r0 + r; if (rr < 8) tagq[rr*112 + colg] = c[r]; }
    }
    f32x4 d = {0.f,0.f,0.f,0.f};
    d = mfma16(a0, wD[0], d); d = mfma16(a1, wD[1], d);
    #pragma unroll
    for (int r = 0; r < 4; ++r) { int rr = r0 + r; if (rr < 8) tagf[rr*128 + colg] = d[r] + bffr; }
  }
  __syncthreads();

  float pA = 0.f, pB = 0.f;   // probs of previous step, stored at top of phase A

  // ==================== recurrence ====================
  for (int i = 1; i < LL; ++i) {
    // ---- Phase A: deferred out-store + q-GEMM (w0-6) + r/ctx-GEMM (w7) ----
    if (i > 1) {
      size_t ob = ((size_t)(i-1)*BB + b)*ALPHA;
      out[ob + lane] = pA; out[ob + 64 + lane] = pB;
    }
    {
      const int arow = lane & 15, koff = (lane >> 4)*8;
      const int r0 = (lane >> 4)*4;
      if (w < 7) {
        f32x4 c = {0.f,0.f,0.f,0.f};
        #pragma unroll
        for (int kt = 0; kt < 5; ++kt)
          c = mfma16(*(const f16x8*)(xq + arow*XQS + kt*32 + koff), wA[kt], c);
        const int colg = w*16 + (lane & 15);
        float pos = posql[i*112 + colg];
        #pragma unroll
        for (int r = 0; r < 4; ++r) {
          int rr = r0 + r;
          if (rr < 8)
            qb[rr*QBS + colg] = (fp16)sigm(c[r] + pos + tagq[rr*112 + colg]);
        }
      } else {
        // r[i-1] = sig(probs[i-1] @ Wre + bre)
        f32x4 c0 = {0.f,0.f,0.f,0.f}, c1 = {0.f,0.f,0.f,0.f};
        #pragma unroll
        for (int kt = 0; kt < 4; ++kt) {
          f16x8 a = *(const f16x8*)(xq + arow*XQS + kt*32 + koff);
          c0 = mfma16(a, wA[kt],     c0);
          c1 = mfma16(a, wA[4 + kt], c1);
        }
        const int cA = lane & 15, cB = 16 + (lane & 15);
        #pragma unroll
        for (int r = 0; r < 4; ++r) {
          int rr = r0 + r;
          if (rr < 8) {
            if (cA < CTX) rp[rr*40 + cA] = (fp16)sigm(c0[r] + brel[cA]);
            if (cB < CTX) rp[rr*40 + cB] = (fp16)sigm(c1[r] + brel[cB]);
          }
        }
        // ctx(i+1) = sig(r[i-1] @ Wbc + bbc)   (same wave: LDS ordering via lgkmcnt)
        f16x8 ar = *(const f16x8*)(rp + arow*40 + koff);
        f32x4 d0 = {0.f,0.f,0.f,0.f}, d1 = {0.f,0.f,0.f,0.f};
        d0 = mfma16(ar, wC[0], d0);
        d1 = mfma16(ar, wC[1], d1);
        #pragma unroll
        for (int r = 0; r < 4; ++r) {
          int rr = r0 + r;
          if (rr < 8) {
            if (cA < CTX) {
              float cv = sigm(d0[r] + bbcl[cA]);
              xq[rr*XQS + 128 + cA] = (fp16)cv;
              xf[rr*XFS + 188 + cA] = (fp16)cv;
            }
            if (cB < CTX) {
              float cv = sigm(d1[r] + bbcl[cB]);
              xq[rr*XQS + 128 + cB] = (fp16)cv;
              xf[rr*XFS + 188 + cB] = (fp16)cv;
            }
          }
        }
      }
    }
    __syncthreads();

    // ---- Phase B (wave e=w): scores, DPP softmax-50, in_attn ----
    {
      const fp16* qrow = qb + w*QBS;
      float a0 = 0.f, a1 = 0.f;
      #pragma unroll
      for (int k = 0; k < 12; k += 2) {
        a0 = dot8f(*(const f16x8*)(qrow + 8*k),     Kr[k],   a0);
        a1 = dot8f(*(const f16x8*)(qrow + 8*(k+1)), Kr[k+1], a1);
      }
      a0 = dot4f(*(const f16x4*)(qrow + 96), Kr12, a0);
      float s = (lane < LL) ? (a0 + a1) : 0.f;      // scores >= 0
      float m  = redmax64(s);
      float e  = (lane < LL) ? __expf(s - m) : 0.f;
      float su = redsum64(e);
      if (lane < LL) atb[w*56 + lane] = (fp16)(e * rcpf(su));
      const fp16* ar = atb + w*56;
      float v0 = 0.f, v1 = 0.f;
      #pragma unroll
      for (int k = 0; k < 12; k += 2) {
        v0 = dot4f(*(const f16x4*)(ar + 4*k),     Vr[k],   v0);
        v1 = dot4f(*(const f16x4*)(ar + 4*(k+1)), Vr[k+1], v1);
      }
      v0 = dot4f(*(const f16x4*)(ar + 48), Vr[12], v0);
      if (lane < 60) xf[w*XFS + 128 + lane] = (fp16)(v0 + v1);
    }
    __syncthreads();

    // ---- Phase C (all waves): s = sig(xf @ Wff + tagf) ----
    {
      const int arow = lane & 15, koff = (lane >> 4)*8;
      f32x4 c = {0.f,0.f,0.f,0.f};
      #pragma unroll
      for (int kt = 0; kt < 7; ++kt)
        c = mfma16(*(const f16x8*)(xf + arow*XFS + kt*32 + koff), wB[kt], c);
      const int r0 = (lane >> 4)*4, colg = w*16 + (lane & 15);
      #pragma unroll
      for (int r = 0; r < 4; ++r) {
        int rr = r0 + r;
        if (rr < 8)
          sc[rr*SCS + colg] = sigm(c[r] + tagf[rr*128 + colg]);
      }
    }
    __syncthreads();

    // ---- Phase D (wave e=w): DPP softmax-128, update probs (out-store deferred) ----
    {
      float v0 = sc[w*SCS + lane], v1 = sc[w*SCS + 64 + lane];  // sigm > 0
      float m = redmax64(fmaxf(v0, v1));
      float e0 = __expf(v0 - m), e1 = __expf(v1 - m);
      float su = redsum64(e0 + e1);
      float inv = rcpf(su);
      pA = e0 * inv; pB = e1 * inv;
      xq[w*XQS + lane] = (fp16)pA; xq[w*XQS + 64 + lane] = (fp16)pB;
      xf[w*XFS + lane] = (fp16)pA; xf[w*XFS + 64 + lane] = (fp16)pB;
    }
    __syncthreads();
  }
  { size_t ob = ((size_t)(LL-1)*BB + b)*ALPHA;
    out[ob + lane] = pA; out[ob + 64 + lane] = pB; }
}

extern "C" void kernel_launch(void* const* d_in, const int* in_sizes, int n_in,
                              void* d_out, int out_size, void* d_ws, size_t ws_size,
                              hipStream_t stream) {
  (void)in_sizes; (void)n_in; (void)out_size; (void)ws_size;
  const int*   lemma = (const int*)  d_in[0];
  const float* tags  = (const float*)d_in[1];
  const float* embT  = (const float*)d_in[2];
  const float* Wce   = (const float*)d_in[3];
  const float* bce   = (const float*)d_in[4];
  const float* Wb4   = (const float*)d_in[5];
  const float* bb4   = (const float*)d_in[6];
  const float* Waft  = (const float*)d_in[7];
  const float* baft  = (const float*)d_in[8];
  const float* Wall  = (const float*)d_in[9];
  const float* ball  = (const float*)d_in[10];
  const float* Wre   = (const float*)d_in[11];
  const float* bre   = (const float*)d_in[12];
  const float* Wbc   = (const float*)d_in[13];
  const float* bbc   = (const float*)d_in[14];
  const float* Wq    = (const float*)d_in[15];
  const float* bq    = (const float*)d_in[16];
  const float* Wk    = (const float*)d_in[17];
  const float* bk    = (const float*)d_in[18];
  const float* Wff   = (const float*)d_in[19];
  const float* bff   = (const float*)d_in[20];
  char* ws = (char*)d_ws;
  float* out = (float*)d_out;

  dt_setup<<<32, 256, 0, stream>>>(embT, Wce, bce, Wq, bq, Wk, bk, Wff, Wre, Wbc, ws);
  dt_encode<<<BB, 256, 0, stream>>>(lemma, Wb4, bb4, Waft, baft, Wall, ball, ws);
  dt_decoder<<<BB/8, 512, 0, stream>>>(ws, tags, Wre, bre, bbc, bff, out);
}